// Round 7
// baseline (1199.538 us; speedup 1.0000x reference)
//
#include <hip/hip_runtime.h>

#define B_ 16
#define T_ 16
#define N_ 1024
#define C_ 48
#define G_ 32
#define H_ 150
#define A_ 32
#define P_ 32
#define H3_ 450
#define NNZ_CAP 262144
#define CAP1 256
#define CAP23 384
#define CHCAP 40960
#define CHCAPL 16384
#define SCALE_ 0.17677669529663687f

__device__ __forceinline__ unsigned fenc(float f){
  unsigned u = __float_as_uint(f);
  return (u & 0x80000000u) ? ~u : (u | 0x80000000u);
}
__device__ __forceinline__ float fdec(unsigned e){
  unsigned u = (e & 0x80000000u) ? (e & 0x7fffffffu) : ~e;
  return __uint_as_float(u);
}
__device__ __forceinline__ float sigmf(float x){ return 1.f/(1.f+__expf(-x)); }
__device__ __forceinline__ float wmaxf(float v){
  #pragma unroll
  for (int d=32; d>0; d>>=1) v = fmaxf(v, __shfl_xor(v,d));
  return v;
}

// ---------------- CSR build for adj (5% dense), prior folded into cval ----------------
__global__ void k_csr_cnt(const float* __restrict__ adj, int* __restrict__ rcnt){
  int m = blockIdx.x; int tid = threadIdx.x;
  int c = 0;
  for (int n = tid; n < N_; n += 256) c += (adj[(size_t)m*N_+n] != 0.f) ? 1 : 0;
  __shared__ int sr[256];
  sr[tid]=c; __syncthreads();
  for (int s=128; s>0; s>>=1){ if (tid<s) sr[tid]+=sr[tid+s]; __syncthreads(); }
  if (tid==0) rcnt[m]=sr[0];
}
__global__ void k_csr_scan(const int* __restrict__ rcnt, int* __restrict__ rowptr){
  int lane = threadIdx.x; // 64 threads
  int s = 0;
  for (int r=0;r<16;++r) s += rcnt[lane*16+r];
  int incl = s;
  for (int d=1; d<64; d<<=1){ int y = __shfl_up(incl, d); if (lane>=d) incl += y; }
  int run = incl - s;
  for (int r=0;r<16;++r){ rowptr[lane*16+r] = run; run += rcnt[lane*16+r]; }
  if (lane==63) rowptr[N_] = incl;
}
__global__ void k_csr_fill(const float* __restrict__ adj, const float* __restrict__ prior,
                           const int* __restrict__ rowptr,
                           int* __restrict__ ccol, float* __restrict__ cval){
  int m = blockIdx.x; int lane = threadIdx.x; // 64
  int base = rowptr[m];
  float pm = prior[m];
  for (int it=0; it<N_/64; ++it){
    int n = it*64+lane;
    float a = adj[(size_t)m*N_+n];
    bool pnz = (a != 0.f);
    unsigned long long mk = __ballot(pnz);
    if (pnz){
      int idx = base + __popcll(mk & ((1ULL<<lane)-1ULL));
      if (idx < NNZ_CAP){ ccol[idx]=n; cval[idx]=a*pm; }
    }
    base += __popcll(mk);
  }
}

// ---------------- mask compaction: lst23 + pos1 + counts ----------------
__global__ void k_masks(const int* __restrict__ divided, int* __restrict__ lst23,
                        int* __restrict__ pos1,
                        int* __restrict__ cnt23, int* __restrict__ cnt1){
  int bt = blockIdx.x; int lane = threadIdx.x; // 64
  int base23=0, base1=0;
  for (int it=0; it<N_/64; ++it){
    int n = it*64+lane;
    const int* dv = &divided[((size_t)bt*N_+n)*3];
    int d0=dv[0], d1=dv[1], d2=dv[2];
    bool p23 = (d1>0)||(d2>0); bool p1 = d0>0;
    unsigned long long mk23 = __ballot(p23);
    unsigned long long mk1  = __ballot(p1);
    unsigned long long ltm = (1ULL<<lane)-1ULL;
    if (p23){ int idx = base23 + __popcll(mk23 & ltm); lst23[(size_t)bt*N_+idx]=n; }
    if (p1){ int idx = base1 + __popcll(mk1 & ltm); pos1[(size_t)bt*N_+n]=idx; }
    base23 += __popcll(mk23); base1 += __popcll(mk1);
  }
  if (lane==0){ cnt23[bt]=base23; cnt1[bt]=base1; }
}

// ---------------- chain extraction: maximal runs of consecutive-t m1 per (b,n) ----------------
__global__ void k_chains(const int* __restrict__ divided, unsigned* __restrict__ chains,
                         int* __restrict__ nch, unsigned* __restrict__ chainsL,
                         int* __restrict__ nchL){
  int idx = blockIdx.x*256 + threadIdx.x;   // over B*N
  if (idx >= B_*N_) return;
  int b = idx >> 10, n = idx & (N_-1);
  unsigned m1m = 0;
  for (int t=0;t<T_;++t){
    int d0 = divided[(((size_t)(b*T_+t))*N_ + n)*3];
    if (d0>0) m1m |= (1u<<t);
  }
  unsigned heads = m1m & ~(m1m<<1);
  int cnt = __popc(heads);
  if (cnt==0) return;
  int base = atomicAdd(nch, cnt);
  unsigned hh = heads;
  while (hh){
    int t0 = __builtin_ctz(hh); hh &= (hh-1u);
    unsigned run = m1m >> t0;
    int len = __builtin_ctz(~run);   // trailing ones = chain length
    unsigned enc = ((unsigned)b<<18)|((unsigned)n<<8)|((unsigned)t0<<4)|(unsigned)(len-1);
    if (base < CHCAP) chains[base] = enc;
    base++;
    if (len >= 2){
      int bl = atomicAdd(nchL, 1);
      if (bl < CHCAPL) chainsL[bl] = enc;
    }
  }
}

// ---------------- weight transposes + fused q-projection matrix M = Wq Wk^T, d = Wk bq ----------------
__global__ void k_wt(const float* __restrict__ W_ih, const float* __restrict__ W_hh,
                     const float* __restrict__ Wq, const float* __restrict__ bq,
                     const float* __restrict__ Wk,
                     float* __restrict__ WihT, float* __restrict__ WhhT,
                     float* __restrict__ Md){
  int idx = blockIdx.x*256+threadIdx.x;
  if (idx < G_*H3_){ int g=idx/H3_, k=idx-g*H3_; WihT[g*H3_+k]=W_ih[(size_t)k*G_+g]; }
  int idx2 = idx - G_*H3_;
  if (idx2>=0 && idx2 < H_*H3_){ int h=idx2/H3_, k=idx2-h*H3_; WhhT[h*H3_+k]=W_hh[(size_t)k*H_+h]; }
  int e = idx - (G_*H3_ + H_*H3_);
  if (e>=0 && e<1024){
    int g=e>>5, gp=e&31;
    float acc=0.f;
    #pragma unroll
    for (int a=0;a<A_;++a) acc = fmaf(Wq[g*A_+a], Wk[gp*A_+a], acc);
    Md[e]=acc;
  }
  int e2 = e - 1024;
  if (e2>=0 && e2<32){
    float acc=0.f;
    #pragma unroll
    for (int a=0;a<A_;++a) acc = fmaf(Wk[e2*A_+a], bq[a], acc);
    Md[1024+e2]=acc;
  }
}

__global__ void k_init(float* __restrict__ om23f, int* __restrict__ nch, int* __restrict__ nchL){
  int i = blockIdx.x*256+threadIdx.x;
  if (i<B_*T_*H_){ om23f[i]=0.f; }
  if (i==0){ *nch = 0; *nchL = 0; }
}

// ---------------- fused agg -> co,no, demand-driven (only rows consumers read) ----------------
__global__ __launch_bounds__(256) void k_cono(
    const float* __restrict__ code_x, const float* __restrict__ neighbors,
    const int* __restrict__ divided,
    const int* __restrict__ rowptr, const int* __restrict__ ccol, const float* __restrict__ cval,
    const float* __restrict__ c_emb, const float* __restrict__ n_emb,
    const float* __restrict__ Wg, const float* __restrict__ bg,
    float* __restrict__ co, float* __restrict__ no_)
{
  __shared__ float sCo[4][C_], sNo[4][C_];
  int w = threadIdx.x >> 6, lane = threadIdx.x & 63;
  int gw = blockIdx.x*4 + w;            // row over B*T*N
  int bt = gw >> 10, m = gw & (N_-1);
  int t = bt & (T_-1);
  const int* dv = &divided[(size_t)gw*3];
  int d0=dv[0], d1=dv[1], d2=dv[2];
  bool needCo = (d0|d1|d2) > 0;                 // read by attn (m23) or GRU (m1)
  bool needNo = (t < T_-1) && (divided[((size_t)(gw+N_))*3+1] > 0); // read as q-source at t+1
  if (!needCo && !needNo) return;               // wave-uniform (wave == row)
  float cxm = code_x[gw], nbm = neighbors[gw];
  float acc = 0.f;
  bool needAcc = (needCo && cxm!=0.f) || (needNo && nbm!=0.f);
  if (needAcc){
    int s = rowptr[m], e = rowptr[m+1];
    if (s > NNZ_CAP) s = NNZ_CAP;
    if (e > NNZ_CAP) e = NNZ_CAP;
    int btN = bt << 10;
    for (int base = s; base < e; base += 64){
      int j = base + lane;
      int cc = 0; float wx = 0.f, wy = 0.f;
      if (j < e){
        cc = ccol[j];
        float cv = cval[j];
        float xs = code_x[btN+cc], ys = neighbors[btN+cc];
        wx = cv*xs; wy = cv*ys;
      }
      unsigned long long mk = __ballot(wx!=0.f || wy!=0.f);
      while (mk){
        int u0 = __builtin_ctzll(mk); mk &= (mk-1ULL);
        int u1 = -1;
        if (mk){ u1 = __builtin_ctzll(mk); mk &= (mk-1ULL); }
        int u1s = (u1>=0)? u1 : u0;
        int n0 = __shfl(cc,u0); float a0x=__shfl(wx,u0), a0y=__shfl(wy,u0);
        int n1 = __shfl(cc,u1s); float a1x=__shfl(wx,u1s), a1y=__shfl(wy,u1s);
        float ce0=0.f,ne0=0.f,ce1=0.f,ne1=0.f;
        if (lane < C_){
          ce0 = c_emb[(size_t)n0*C_+lane]; ne0 = n_emb[(size_t)n0*C_+lane];
          ce1 = c_emb[(size_t)n1*C_+lane]; ne1 = n_emb[(size_t)n1*C_+lane];
        }
        acc = fmaf(a0x, ce0, acc); acc = fmaf(a0y, ne0, acc);
        if (u1>=0){ acc = fmaf(a1x, ce1, acc); acc = fmaf(a1y, ne1, acc); }
      }
    }
  }
  if (lane < C_){
    sCo[w][lane] = cxm * (c_emb[(size_t)m*C_+lane] + acc);
    sNo[w][lane] = nbm * (n_emb[(size_t)m*C_+lane] + acc);
  }
  asm volatile("s_waitcnt lgkmcnt(0)" ::: "memory");   // wave-local LDS fence
  int g = lane & 31; bool isNo = lane >= 32;
  const float* src = isNo ? sNo[w] : sCo[w];
  float a2 = bg[g];
  #pragma unroll
  for (int c=0;c<C_;++c) a2 = fmaf(src[c], Wg[c*G_+g], a2);
  float r = a2 >= 0.f ? a2 : 0.01f*a2;
  if (isNo ? needNo : needCo){
    float* dst = isNo ? no_ : co;
    dst[(size_t)gw*G_ + g] = r;
  }
}

// ---------------- attention: one block per (b,t>=1), thread-per-row, LDS broadcast ----------------
__global__ __launch_bounds__(384) void k_attn(
    const float* __restrict__ co, const float* __restrict__ no_,
    const float* __restrict__ u_emb, const int* __restrict__ divided,
    const int* __restrict__ lst23, const int* __restrict__ cnt23, const int* __restrict__ pos1,
    const float* __restrict__ Md, const float* __restrict__ Wv, const float* __restrict__ bv,
    float* __restrict__ hsel, float* __restrict__ om23f)
{
  int b = blockIdx.x; int t = blockIdx.y + 1; int bt = b*T_ + t;
  int cnt = cnt23[bt]; if (cnt > CAP23) cnt = CAP23;
  if (cnt == 0) return;
  __shared__ int   sLst[CAP23];
  __shared__ __align__(16) float sCo[CAP23][G_];   // 48KB
  __shared__ __align__(16) float sW[G_*H_ + H_ + 8];
  __shared__ unsigned sMax[H_];
  int tid = threadIdx.x; int lane = tid & 63;
  for (int i=tid; i<cnt; i+=384) sLst[i] = lst23[(size_t)bt*N_+i];
  for (int i=tid; i<1056; i+=384) sW[i] = Md[i];
  unsigned sent = fenc(-1e30f);
  for (int i=tid; i<H_; i+=384) sMax[i] = sent;
  __syncthreads();
  for (int i=tid; i<cnt*8; i+=384){
    int rrow = i>>3, seg = i&7;
    float4 v = *(const float4*)&co[((((size_t)bt<<10) + sLst[rrow])<<5) + seg*4];
    *(float4*)&sCo[rrow][seg*4] = v;
  }
  bool act = (tid < cnt);
  int n = 0;
  float qpp[G_];
  if (act){
    n = sLst[tid];
    int d1 = divided[((size_t)bt*N_+n)*3+1];
    const float* qsrc = (d1>0) ? &no_[((((size_t)(bt-1))<<10)+n)<<5] : &u_emb[(size_t)n*G_];
    float4 qv[8];
    #pragma unroll
    for (int j=0;j<8;++j) qv[j] = ((const float4*)qsrc)[j];
    #pragma unroll
    for (int j=0;j<G_;++j) qpp[j] = sW[1024+j];
    #pragma unroll
    for (int g=0; g<G_; ++g){
      float qfg = (g&3)==0 ? qv[g>>2].x : (g&3)==1 ? qv[g>>2].y : (g&3)==2 ? qv[g>>2].z : qv[g>>2].w;
      const float4* mr = (const float4*)&sW[g*G_];
      #pragma unroll
      for (int j=0;j<8;++j){
        float4 mj = mr[j];
        qpp[4*j+0] = fmaf(qfg, mj.x, qpp[4*j+0]);
        qpp[4*j+1] = fmaf(qfg, mj.y, qpp[4*j+1]);
        qpp[4*j+2] = fmaf(qfg, mj.z, qpp[4*j+2]);
        qpp[4*j+3] = fmaf(qfg, mj.w, qpp[4*j+3]);
      }
    }
  } else {
    #pragma unroll
    for (int j=0;j<G_;++j) qpp[j]=0.f;
  }
  __syncthreads();
  for (int i=tid; i<G_*H_; i+=384){
    int h=i>>5, g=i&31;
    sW[h*G_+g] = Wv[(size_t)g*H_+h];
  }
  for (int i=tid; i<H_; i+=384) sW[G_*H_+i] = bv[i];
  float pbar[G_]; float l = 0.f;
  #pragma unroll
  for (int j=0;j<G_;++j) pbar[j]=0.f;
  if (act){
    #pragma unroll 2
    for (int c=0;c<cnt;++c){
      const float4* col = (const float4*)&sCo[c][0];
      float4 xv[8];
      #pragma unroll
      for (int j=0;j<8;++j) xv[j]=col[j];
      float d0=0.f,d1v=0.f,d2v=0.f,d3=0.f;
      #pragma unroll
      for (int j=0;j<8;j+=4){
        d0 = fmaf(qpp[4*j+0], xv[j].x, d0); d1v = fmaf(qpp[4*j+1], xv[j].y, d1v);
        d2v = fmaf(qpp[4*j+2], xv[j].z, d2v); d3 = fmaf(qpp[4*j+3], xv[j].w, d3);
        d0 = fmaf(qpp[4*j+4], xv[j+1].x, d0); d1v = fmaf(qpp[4*j+5], xv[j+1].y, d1v);
        d2v = fmaf(qpp[4*j+6], xv[j+1].z, d2v); d3 = fmaf(qpp[4*j+7], xv[j+1].w, d3);
        d0 = fmaf(qpp[4*j+8], xv[j+2].x, d0); d1v = fmaf(qpp[4*j+9], xv[j+2].y, d1v);
        d2v = fmaf(qpp[4*j+10], xv[j+2].z, d2v); d3 = fmaf(qpp[4*j+11], xv[j+2].w, d3);
        d0 = fmaf(qpp[4*j+12], xv[j+3].x, d0); d1v = fmaf(qpp[4*j+13], xv[j+3].y, d1v);
        d2v = fmaf(qpp[4*j+14], xv[j+3].z, d2v); d3 = fmaf(qpp[4*j+15], xv[j+3].w, d3);
      }
      float dot = (d0+d1v)+(d2v+d3);
      float pv = __expf(dot*SCALE_);
      l += pv;
      #pragma unroll
      for (int j=0;j<8;++j){
        pbar[4*j+0] = fmaf(pv, xv[j].x, pbar[4*j+0]);
        pbar[4*j+1] = fmaf(pv, xv[j].y, pbar[4*j+1]);
        pbar[4*j+2] = fmaf(pv, xv[j].z, pbar[4*j+2]);
        pbar[4*j+3] = fmaf(pv, xv[j].w, pbar[4*j+3]);
      }
    }
  }
  if (!act) l = 1.f;
  float inv = 1.f/l;
  #pragma unroll
  for (int j=0;j<G_;++j) pbar[j]*=inv;
  __syncthreads();
  bool wsel=false; float* hd=nullptr;
  if (act && t+1 < T_){
    size_t nidx = ((size_t)b*T_+(t+1))*N_ + n;
    if (divided[nidx*3+0] > 0){
      int pos = pos1[nidx];
      if (pos >= 0 && pos < CAP1){ wsel=true; hd=&hsel[(((size_t)b*T_+t)*CAP1 + pos)*H_]; }
    }
  }
  for (int h=0; h<H_; ++h){
    float acc = sW[G_*H_+h];
    const float4* wv = (const float4*)&sW[h*G_];
    #pragma unroll
    for (int j=0;j<8;++j){
      float4 wj = wv[j];
      acc = fmaf(pbar[4*j+0], wj.x, acc);
      acc = fmaf(pbar[4*j+1], wj.y, acc);
      acc = fmaf(pbar[4*j+2], wj.z, acc);
      acc = fmaf(pbar[4*j+3], wj.w, acc);
    }
    float o = act ? tanhf(acc) : -1e30f;
    float om = wmaxf(o);
    if (lane==0) atomicMax(&sMax[h], fenc(om));
    if (wsel) hd[h] = o;
  }
  __syncthreads();
  for (int i=tid; i<H_; i+=384) om23f[(size_t)bt*H_+i] = fdec(sMax[i]);
}

// ---------------- GRU chain HEADS: 16 chains/block, dense gate GEMM (~51KB LDS) ----------------
__global__ __launch_bounds__(256) void k_gruhead(
    const float* __restrict__ co, const float* __restrict__ hsel,
    const int* __restrict__ divided, const int* __restrict__ pos1,
    const unsigned* __restrict__ chains, const int* __restrict__ nch,
    const float* __restrict__ WihT, const float* __restrict__ b_ih,
    const float* __restrict__ WhhT, const float* __restrict__ b_hh,
    float* __restrict__ gout)
{
  __shared__ float sCo[16][G_];    // 2KB
  __shared__ float sH[16][152];    // 9.73KB (zeroed; h_prev for active slots)
  __shared__ float sG[16][452];    // 28.93KB (r,z: ih+hh summed; n: ih only)
  __shared__ float sGhn[16][152];  // 9.73KB (hh n-gate; 0 for inactive)
  __shared__ int tBt[16], tN[16], tPos[16], tF[16], tHoff[16], sSlot[16];
  __shared__ int sBt[16], sPos[16];
  __shared__ int sNa;
  int tid = threadIdx.x;
  int NC = *nch; if (NC > CHCAP) NC = CHCAP;
  int base = blockIdx.x * 16;
  if (base >= NC) return;
  int num = min(16, NC - base);
  if (tid < num){
    unsigned cl = chains[base+tid];
    int b = cl>>18, n = (cl>>8)&1023, t0 = (cl>>4)&15;
    int bt = b*T_ + t0;
    int pos = pos1[(size_t)bt*N_ + n];
    int f = 0, hoff = 0;
    if (t0 >= 2 && pos >= 0 && pos < CAP1){
      size_t pidx = ((size_t)(bt-1)*N_ + n)*3;
      if ((divided[pidx+1] | divided[pidx+2]) > 0){
        f = 1; hoff = (b*T_ + (t0-1))*CAP1 + pos;
      }
    }
    tBt[tid]=bt; tN[tid]=n; tPos[tid]=pos; tF[tid]=f; tHoff[tid]=hoff;
  }
  __syncthreads();
  if (tid == 0){
    int lo = 0, hi = num-1;
    for (int i=0;i<num;++i) sSlot[i] = tF[i] ? lo++ : hi--;
    sNa = lo;
  }
  __syncthreads();
  if (tid < num){
    int s = sSlot[tid];
    sBt[s]=tBt[tid]; sPos[s]=tPos[tid];
  }
  for (int i=tid; i<16*152; i+=256) (&sH[0][0])[i] = 0.f;
  __syncthreads();
  // cooperative gathers
  for (int i=tid; i<num*G_; i+=256){
    int ii = i>>5, g = i&31;
    sCo[sSlot[ii]][g] = co[((size_t)tBt[ii]*N_ + tN[ii])*G_ + g];
  }
  for (int i=tid; i<num*152; i+=256){
    int ii = i/152, q = i - ii*152;
    if (tF[ii] && q < H_)
      sH[sSlot[ii]][q] = hsel[(size_t)tHoff[ii]*H_ + q];
  }
  __syncthreads();
  int na = sNa;
  // gate GEMMs: thread k over 450 outputs, 16-slot register reuse
  for (int pass=0; pass<2; ++pass){
    int k = pass*256 + tid;
    if (k < H3_){
      float acc[16];
      #pragma unroll
      for (int u=0;u<16;++u) acc[u]=0.f;
      for (int g=0; g<G_; ++g){
        float wih = WihT[g*H3_ + k];
        #pragma unroll
        for (int u=0;u<16;++u) acc[u] = fmaf(wih, sCo[u][g], acc[u]);
      }
      float hh[16];
      #pragma unroll
      for (int u=0;u<16;++u) hh[u]=0.f;
      #pragma unroll
      for (int ug=0; ug<4; ++ug){
        if (ug*4 < na){
          float g4[4] = {0.f,0.f,0.f,0.f};
          for (int q=0; q<H_; ++q){
            float whh = WhhT[q*H3_ + k];
            #pragma unroll
            for (int v=0;v<4;++v) g4[v] = fmaf(whh, sH[ug*4+v][q], g4[v]);
          }
          #pragma unroll
          for (int v=0;v<4;++v) hh[ug*4+v] = g4[v];
        }
      }
      if (k < 2*H_){
        #pragma unroll
        for (int u=0;u<16;++u) sG[u][k] = acc[u] + hh[u];
      } else {
        #pragma unroll
        for (int u=0;u<16;++u){ sG[u][k] = acc[u]; sGhn[u][k-2*H_] = hh[u]; }
      }
    }
  }
  __syncthreads();
  // branchless elementwise GRU combine -> gout (sH/hh zeroed handle no-h case)
  for (int i=tid; i<num*152; i+=256){
    int s = i/152, h = i - s*152;
    if (h < H_){
      int pos = sPos[s];
      if (pos >= 0 && pos < CAP1){
        float r = sigmf(sG[s][h]       + b_ih[h]       + b_hh[h]);
        float z = sigmf(sG[s][h+H_]    + b_ih[h+H_]    + b_hh[h+H_]);
        float cand = tanhf(sG[s][h+2*H_] + b_ih[h+2*H_] + r*(sGhn[s][h] + b_hh[h+2*H_]));
        float o = (1.f-z)*cand + z*sH[s][h];
        gout[((size_t)sBt[s]*CAP1 + pos)*H_ + h] = o;
      }
    }
  }
}

// ---------------- GRU chain TAILS (len>=2): serial walk s=1.., 4 chains/wave ----------------
__global__ __launch_bounds__(256) void k_grutail(
    const float* __restrict__ co, const int* __restrict__ pos1,
    const unsigned* __restrict__ chainsL, const int* __restrict__ nchL,
    const float* __restrict__ WihT, const float* __restrict__ b_ih,
    const float* __restrict__ WhhT, const float* __restrict__ b_hh,
    float* __restrict__ gout)
{
  __shared__ float hst[4][4][H_];   // 9.6KB
  int w = threadIdx.x >> 6, lane = threadIdx.x & 63;
  int NC = *nchL; if (NC > CHCAPL) NC = CHCAPL;
  int cbase = (blockIdx.x*4 + w)*4;
  if (cbase >= NC) return;

  int cbv[4], cnv[4], t0v[4], lenv[4];
  #pragma unroll
  for (int u=0;u<4;++u){
    int cid = cbase+u; bool ca = cid < NC;
    unsigned cl = chainsL[ca ? cid : (NC-1)];
    cbv[u]=cl>>18; cnv[u]=(cl>>8)&1023; t0v[u]=(cl>>4)&15;
    lenv[u]= ca ? (int)((cl&15)+1) : 1;   // inactive -> len 1 -> no s>=1 steps
  }
  int maxlen = lenv[0];
  #pragma unroll
  for (int u=1;u<4;++u) maxlen = max(maxlen, lenv[u]);

  int h0=lane,h1=lane+64,h2=lane+128; bool has2=(h2<H_); int h2c=has2?h2:0;
  float bi[9], bh[9];
  bi[0]=b_ih[h0]; bi[1]=b_ih[h0+H_]; bi[2]=b_ih[h0+2*H_];
  bi[3]=b_ih[h1]; bi[4]=b_ih[h1+H_]; bi[5]=b_ih[h1+2*H_];
  bi[6]=b_ih[h2c]; bi[7]=b_ih[h2c+H_]; bi[8]=b_ih[h2c+2*H_];
  bh[0]=b_hh[h0]; bh[1]=b_hh[h0+H_]; bh[2]=b_hh[h0+2*H_];
  bh[3]=b_hh[h1]; bh[4]=b_hh[h1+H_]; bh[5]=b_hh[h1+2*H_];
  bh[6]=b_hh[h2c]; bh[7]=b_hh[h2c+H_]; bh[8]=b_hh[h2c+2*H_];

  for (int s=1; s<maxlen; ++s){
    bool as[4]; int btv[4];
    const float* hp[4];
    #pragma unroll
    for (int u=0;u<4;++u){
      as[u] = s < lenv[u];
      int t = t0v[u] + (as[u] ? s : 0);
      btv[u] = cbv[u]*T_ + t;
      if (s == 1 && as[u]){
        // head output from gout (head is m1 at btv-1, pos1 valid there)
        int btp = btv[u] - 1;
        int posp = pos1[(size_t)btp*N_ + cnv[u]];
        if (posp < 0 || posp >= CAP1) posp = 0;
        hp[u] = &gout[((size_t)btp*CAP1 + posp)*H_];
      } else {
        hp[u] = &hst[w][u][0];
      }
    }
    float gi[4][9], gh[4][9];
    #pragma unroll
    for (int u=0;u<4;++u){
      #pragma unroll
      for (int j=0;j<9;++j){ gi[u][j]=bi[j]; gh[u][j]=bh[j]; }
    }
    const float* cop[4];
    #pragma unroll
    for (int u=0;u<4;++u) cop[u] = &co[((size_t)btv[u]*N_ + cnv[u])*G_];
    for (int g=0; g<G_; ++g){
      const float* wr = &WihT[g*H3_];
      float wv[9];
      wv[0]=wr[h0]; wv[1]=wr[h0+H_]; wv[2]=wr[h0+2*H_];
      wv[3]=wr[h1]; wv[4]=wr[h1+H_]; wv[5]=wr[h1+2*H_];
      wv[6]=wr[h2c]; wv[7]=wr[h2c+H_]; wv[8]=wr[h2c+2*H_];
      #pragma unroll
      for (int u=0;u<4;++u){
        float cg = cop[u][g];
        #pragma unroll
        for (int j=0;j<9;++j) gi[u][j]=fmaf(cg, wv[j], gi[u][j]);
      }
    }
    for (int q=0;q<H_;++q){
      const float* wr=&WhhT[q*H3_];
      float wv[9];
      wv[0]=wr[h0]; wv[1]=wr[h0+H_]; wv[2]=wr[h0+2*H_];
      wv[3]=wr[h1]; wv[4]=wr[h1+H_]; wv[5]=wr[h1+2*H_];
      wv[6]=wr[h2c]; wv[7]=wr[h2c+H_]; wv[8]=wr[h2c+2*H_];
      #pragma unroll
      for (int u=0;u<4;++u){
        float hv = hp[u][q];
        #pragma unroll
        for (int j=0;j<9;++j) gh[u][j]=fmaf(hv, wv[j], gh[u][j]);
      }
    }
    #pragma unroll
    for (int u=0;u<4;++u){
      if (as[u]){
        float hv0 = hp[u][h0];
        float hv1 = hp[u][h1];
        float hv2 = has2 ? hp[u][h2] : 0.f;
        float r0=sigmf(gi[u][0]+gh[u][0]), z0=sigmf(gi[u][1]+gh[u][1]);
        float cd0=tanhf(gi[u][2]+r0*gh[u][2]);
        float o0=(1.f-z0)*cd0 + z0*hv0;
        float r1=sigmf(gi[u][3]+gh[u][3]), z1=sigmf(gi[u][4]+gh[u][4]);
        float cd1=tanhf(gi[u][5]+r1*gh[u][5]);
        float o1=(1.f-z1)*cd1 + z1*hv1;
        float o2=0.f;
        if (has2){
          float r2=sigmf(gi[u][6]+gh[u][6]), z2=sigmf(gi[u][7]+gh[u][7]);
          float cd2=tanhf(gi[u][8]+r2*gh[u][8]);
          o2=(1.f-z2)*cd2 + z2*hv2;
        }
        float* hd = &hst[w][u][0];
        hd[h0]=o0; hd[h1]=o1; if (has2) hd[h2]=o2;
        int pos = pos1[(size_t)btv[u]*N_ + cnv[u]];
        if (pos >= 0 && pos < CAP1){
          float* gd = &gout[((size_t)btv[u]*CAP1 + pos)*H_];
          gd[h0]=o0; gd[h1]=o1; if (has2) gd[h2]=o2;
        }
      }
    }
    asm volatile("s_waitcnt lgkmcnt(0)" ::: "memory");  // h stores visible before next s reads
  }
}

// ---------------- per-(b,t) max over m1 rows -> om1f ----------------
__global__ __launch_bounds__(256) void k_om1(
    const float* __restrict__ gout, const int* __restrict__ cnt1, float* __restrict__ om1f)
{
  int bt = blockIdx.x; int tid = threadIdx.x;
  int c1 = cnt1[bt]; if (c1 > CAP1) c1 = CAP1;
  if (tid < H_){
    float mx = -1e30f;
    for (int r=0;r<c1;++r) mx = fmaxf(mx, gout[((size_t)bt*CAP1+r)*H_+tid]);
    om1f[(size_t)bt*H_+tid] = (c1>0) ? mx : 0.f;
  }
}

// ---------------- final: outs assembly, pooling, output ----------------
__global__ __launch_bounds__(256) void k_final(
    const float* __restrict__ om1f, const float* __restrict__ om23f,
    const float* __restrict__ Wp, const float* __restrict__ bp,
    const float* __restrict__ ctx, const float* __restrict__ Wc, const float* __restrict__ bc,
    const int* __restrict__ lens, float* __restrict__ out)
{
  int b = blockIdx.x; int tid = threadIdx.x;
  __shared__ float sOut[T_][H_];
  __shared__ float sTP[T_][P_];
  __shared__ float sVu[T_], sSc[T_], sPool[H_];
  __shared__ float sRed[256];
  for (int i=tid; i<T_*H_; i+=256){
    int t=i/H_, h=i-t*H_;
    float o1 = om1f[((size_t)b*T_+t)*H_+h];
    float o2 = (t>0)? om23f[((size_t)b*T_+t)*H_+h] : 0.f;
    sOut[t][h]=o1+o2;
  }
  __syncthreads();
  for (int pr = tid; pr < T_*P_; pr += 256){
    int t = pr / P_, p = pr - t*P_;
    float acc = bp[p];
    for (int h=0;h<H_;++h) acc = fmaf(sOut[t][h], Wp[h*P_+p], acc);
    sTP[t][p] = acc * ctx[p];
  }
  __syncthreads();
  if (tid < T_){
    float v=0.f;
    for (int p=0;p<P_;++p) v += sTP[tid][p];
    sVu[tid]=v;
  }
  __syncthreads();
  if (tid==0){
    int L = lens[b]; if (L<1) L=1; if (L>T_) L=T_;
    float mx=-1e30f;
    for (int t=0;t<L;++t) mx = fmaxf(mx, sVu[t]);
    float s=0.f;
    for (int t=0;t<L;++t){ float e=__expf(sVu[t]-mx); sSc[t]=e; s+=e; }
    float inv=1.f/s;
    for (int t=0;t<T_;++t) sSc[t] = (t<L)? sSc[t]*inv : 0.f;
  }
  __syncthreads();
  if (tid < H_){
    float acc=0.f;
    for (int t=0;t<T_;++t) acc = fmaf(sOut[t][tid], sSc[t], acc);
    sPool[tid]=acc;
  }
  __syncthreads();
  float v = (tid<H_)? sPool[tid]*Wc[tid] : 0.f;
  sRed[tid]=v; __syncthreads();
  for (int s=128;s>0;s>>=1){ if (tid<s) sRed[tid]+=sRed[tid+s]; __syncthreads(); }
  if (tid==0) out[b] = sRed[0] + bc[0];
}

extern "C" void kernel_launch(void* const* d_in, const int* in_sizes, int n_in,
                              void* d_out, int out_size, void* d_ws, size_t ws_size,
                              hipStream_t stream)
{
  const float* code_x=(const float*)d_in[0];
  const int*   divided=(const int*)d_in[1];
  const float* neighbors=(const float*)d_in[2];
  const int*   lens=(const int*)d_in[3];
  const float* prior=(const float*)d_in[4];
  const float* adj=(const float*)d_in[5];
  const float* c_emb=(const float*)d_in[6];
  const float* n_emb=(const float*)d_in[7];
  const float* u_emb=(const float*)d_in[8];
  const float* Wg=(const float*)d_in[9];
  const float* bg=(const float*)d_in[10];
  const float* W_ih=(const float*)d_in[11];
  const float* b_ih=(const float*)d_in[12];
  const float* W_hh=(const float*)d_in[13];
  const float* b_hh=(const float*)d_in[14];
  const float* Wq=(const float*)d_in[15];
  const float* bq=(const float*)d_in[16];
  const float* Wk=(const float*)d_in[17];
  const float* bk=(const float*)d_in[18];
  const float* Wv=(const float*)d_in[19];
  const float* bv=(const float*)d_in[20];
  const float* Wp=(const float*)d_in[21];
  const float* bp=(const float*)d_in[22];
  const float* ctx=(const float*)d_in[23];
  const float* Wc=(const float*)d_in[24];
  const float* bc=(const float*)d_in[25];
  float* out=(float*)d_out;
  (void)in_sizes; (void)n_in; (void)out_size; (void)ws_size; (void)bk;

  char* p=(char*)d_ws;
  size_t off=0;
  auto carve=[&](size_t bytes)->char*{ char* r=p+off; off=(off+bytes+255)&~(size_t)255; return r; };
  int*   rowptr=(int*)carve((N_+1)*4);
  int*   rcnt  =(int*)carve(N_*4);
  int*   ccol  =(int*)carve((size_t)NNZ_CAP*4);
  float* cval  =(float*)carve((size_t)NNZ_CAP*4);
  int*   cnt23 =(int*)carve(B_*T_*4);
  int*   cnt1  =(int*)carve(B_*T_*4);
  int*   lst23 =(int*)carve((size_t)B_*T_*N_*4);
  int*   pos1  =(int*)carve((size_t)B_*T_*N_*4);
  float* co    =(float*)carve((size_t)B_*T_*N_*G_*4);
  float* no_   =(float*)carve((size_t)B_*T_*N_*G_*4);
  float* WihT  =(float*)carve((size_t)G_*H3_*4);
  float* WhhT  =(float*)carve((size_t)H_*H3_*4);
  float* Md    =(float*)carve(1056*4);
  float* hsel  =(float*)carve((size_t)B_*T_*CAP1*H_*4);
  float* gout  =(float*)carve((size_t)B_*T_*CAP1*H_*4);
  unsigned* chains=(unsigned*)carve((size_t)CHCAP*4);
  unsigned* chainsL=(unsigned*)carve((size_t)CHCAPL*4);
  int*   nch   =(int*)carve(256);
  int*   nchL  =(int*)carve(256);
  float* om1f  =(float*)carve((size_t)B_*T_*H_*4);
  float* om23f =(float*)carve((size_t)B_*T_*H_*4);

  k_csr_cnt<<<N_,256,0,stream>>>(adj, rcnt);
  k_csr_scan<<<1,64,0,stream>>>(rcnt, rowptr);
  k_csr_fill<<<N_,64,0,stream>>>(adj, prior, rowptr, ccol, cval);
  k_masks<<<B_*T_,64,0,stream>>>(divided, lst23, pos1, cnt23, cnt1);
  k_wt<<<325,256,0,stream>>>(W_ih, W_hh, Wq, bq, Wk, WihT, WhhT, Md);
  k_init<<<(B_*T_*H_+255)/256,256,0,stream>>>(om23f, nch, nchL);
  k_chains<<<(B_*N_+255)/256,256,0,stream>>>(divided, chains, nch, chainsL, nchL);
  k_cono<<<B_*T_*N_/4,256,0,stream>>>(code_x, neighbors, divided, rowptr, ccol, cval,
                                      c_emb, n_emb, Wg, bg, co, no_);
  k_attn<<<dim3(B_, T_-1),384,0,stream>>>(co, no_, u_emb, divided,
                                      lst23, cnt23, pos1, Md, Wv, bv,
                                      hsel, om23f);
  k_gruhead<<<CHCAP/16,256,0,stream>>>(co, hsel, divided, pos1, chains, nch,
                                      WihT, b_ih, WhhT, b_hh, gout);
  k_grutail<<<CHCAPL/16,256,0,stream>>>(co, pos1, chainsL, nchL,
                                      WihT, b_ih, WhhT, b_hh, gout);
  k_om1<<<B_*T_,256,0,stream>>>(gout, cnt1, om1f);
  k_final<<<B_,256,0,stream>>>(om1f, om23f, Wp,bp,ctx,Wc,bc, lens, out);
}

// Round 8
// 699.947 us; speedup vs baseline: 1.7138x; 1.7138x over previous
//
#include <hip/hip_runtime.h>

#define B_ 16
#define T_ 16
#define N_ 1024
#define C_ 48
#define G_ 32
#define H_ 150
#define A_ 32
#define P_ 32
#define H3_ 450
#define NNZ_CAP 262144
#define CAP1 256
#define CAP23 384
#define CHCAP 40960
#define CHCAPL 16384
#define SCALE_ 0.17677669529663687f

__device__ __forceinline__ unsigned fenc(float f){
  unsigned u = __float_as_uint(f);
  return (u & 0x80000000u) ? ~u : (u | 0x80000000u);
}
__device__ __forceinline__ float fdec(unsigned e){
  unsigned u = (e & 0x80000000u) ? (e & 0x7fffffffu) : ~e;
  return __uint_as_float(u);
}
__device__ __forceinline__ float sigmf(float x){ return 1.f/(1.f+__expf(-x)); }
__device__ __forceinline__ float wmaxf(float v){
  #pragma unroll
  for (int d=32; d>0; d>>=1) v = fmaxf(v, __shfl_xor(v,d));
  return v;
}

// ---------------- CSR build for adj (5% dense), prior folded into cval ----------------
__global__ void k_csr_cnt(const float* __restrict__ adj, int* __restrict__ rcnt){
  int m = blockIdx.x; int tid = threadIdx.x;
  int c = 0;
  for (int n = tid; n < N_; n += 256) c += (adj[(size_t)m*N_+n] != 0.f) ? 1 : 0;
  __shared__ int sr[256];
  sr[tid]=c; __syncthreads();
  for (int s=128; s>0; s>>=1){ if (tid<s) sr[tid]+=sr[tid+s]; __syncthreads(); }
  if (tid==0) rcnt[m]=sr[0];
}
__global__ void k_csr_scan(const int* __restrict__ rcnt, int* __restrict__ rowptr){
  int lane = threadIdx.x; // 64 threads
  int s = 0;
  for (int r=0;r<16;++r) s += rcnt[lane*16+r];
  int incl = s;
  for (int d=1; d<64; d<<=1){ int y = __shfl_up(incl, d); if (lane>=d) incl += y; }
  int run = incl - s;
  for (int r=0;r<16;++r){ rowptr[lane*16+r] = run; run += rcnt[lane*16+r]; }
  if (lane==63) rowptr[N_] = incl;
}
__global__ void k_csr_fill(const float* __restrict__ adj, const float* __restrict__ prior,
                           const int* __restrict__ rowptr,
                           int* __restrict__ ccol, float* __restrict__ cval){
  int m = blockIdx.x; int lane = threadIdx.x; // 64
  int base = rowptr[m];
  float pm = prior[m];
  for (int it=0; it<N_/64; ++it){
    int n = it*64+lane;
    float a = adj[(size_t)m*N_+n];
    bool pnz = (a != 0.f);
    unsigned long long mk = __ballot(pnz);
    if (pnz){
      int idx = base + __popcll(mk & ((1ULL<<lane)-1ULL));
      if (idx < NNZ_CAP){ ccol[idx]=n; cval[idx]=a*pm; }
    }
    base += __popcll(mk);
  }
}

// ---------------- mask compaction: lst23 + pos1 + counts ----------------
__global__ void k_masks(const int* __restrict__ divided, int* __restrict__ lst23,
                        int* __restrict__ pos1,
                        int* __restrict__ cnt23, int* __restrict__ cnt1){
  int bt = blockIdx.x; int lane = threadIdx.x; // 64
  int base23=0, base1=0;
  for (int it=0; it<N_/64; ++it){
    int n = it*64+lane;
    const int* dv = &divided[((size_t)bt*N_+n)*3];
    int d0=dv[0], d1=dv[1], d2=dv[2];
    bool p23 = (d1>0)||(d2>0); bool p1 = d0>0;
    unsigned long long mk23 = __ballot(p23);
    unsigned long long mk1  = __ballot(p1);
    unsigned long long ltm = (1ULL<<lane)-1ULL;
    if (p23){ int idx = base23 + __popcll(mk23 & ltm); lst23[(size_t)bt*N_+idx]=n; }
    if (p1){ int idx = base1 + __popcll(mk1 & ltm); pos1[(size_t)bt*N_+n]=idx; }
    base23 += __popcll(mk23); base1 += __popcll(mk1);
  }
  if (lane==0){ cnt23[bt]=base23; cnt1[bt]=base1; }
}

// ---------------- chain extraction: maximal runs of consecutive-t m1 per (b,n) ----------------
__global__ void k_chains(const int* __restrict__ divided, unsigned* __restrict__ chains,
                         int* __restrict__ nch, unsigned* __restrict__ chainsL,
                         int* __restrict__ nchL){
  int idx = blockIdx.x*256 + threadIdx.x;   // over B*N
  if (idx >= B_*N_) return;
  int b = idx >> 10, n = idx & (N_-1);
  unsigned m1m = 0;
  for (int t=0;t<T_;++t){
    int d0 = divided[(((size_t)(b*T_+t))*N_ + n)*3];
    if (d0>0) m1m |= (1u<<t);
  }
  unsigned heads = m1m & ~(m1m<<1);
  int cnt = __popc(heads);
  if (cnt==0) return;
  int base = atomicAdd(nch, cnt);
  unsigned hh = heads;
  while (hh){
    int t0 = __builtin_ctz(hh); hh &= (hh-1u);
    unsigned run = m1m >> t0;
    int len = __builtin_ctz(~run);   // trailing ones = chain length
    unsigned enc = ((unsigned)b<<18)|((unsigned)n<<8)|((unsigned)t0<<4)|(unsigned)(len-1);
    if (base < CHCAP) chains[base] = enc;
    base++;
    if (len >= 2){
      int bl = atomicAdd(nchL, 1);
      if (bl < CHCAPL) chainsL[bl] = enc;
    }
  }
}

// ---------------- weight transposes + fused q-projection matrix M = Wq Wk^T, d = Wk bq ----------------
__global__ void k_wt(const float* __restrict__ W_ih, const float* __restrict__ W_hh,
                     const float* __restrict__ Wq, const float* __restrict__ bq,
                     const float* __restrict__ Wk,
                     float* __restrict__ WihT, float* __restrict__ WhhT,
                     float* __restrict__ Md){
  int idx = blockIdx.x*256+threadIdx.x;
  if (idx < G_*H3_){ int g=idx/H3_, k=idx-g*H3_; WihT[g*H3_+k]=W_ih[(size_t)k*G_+g]; }
  int idx2 = idx - G_*H3_;
  if (idx2>=0 && idx2 < H_*H3_){ int h=idx2/H3_, k=idx2-h*H3_; WhhT[h*H3_+k]=W_hh[(size_t)k*H_+h]; }
  int e = idx - (G_*H3_ + H_*H3_);
  if (e>=0 && e<1024){
    int g=e>>5, gp=e&31;
    float acc=0.f;
    #pragma unroll
    for (int a=0;a<A_;++a) acc = fmaf(Wq[g*A_+a], Wk[gp*A_+a], acc);
    Md[e]=acc;
  }
  int e2 = e - 1024;
  if (e2>=0 && e2<32){
    float acc=0.f;
    #pragma unroll
    for (int a=0;a<A_;++a) acc = fmaf(Wk[e2*A_+a], bq[a], acc);
    Md[1024+e2]=acc;
  }
}

__global__ void k_init(float* __restrict__ om23f, int* __restrict__ nch, int* __restrict__ nchL){
  int i = blockIdx.x*256+threadIdx.x;
  if (i<B_*T_*H_){ om23f[i]=0.f; }
  if (i==0){ *nch = 0; *nchL = 0; }
}

// ---------------- fused agg -> co,no, demand-driven (only rows consumers read) ----------------
__global__ __launch_bounds__(256) void k_cono(
    const float* __restrict__ code_x, const float* __restrict__ neighbors,
    const int* __restrict__ divided,
    const int* __restrict__ rowptr, const int* __restrict__ ccol, const float* __restrict__ cval,
    const float* __restrict__ c_emb, const float* __restrict__ n_emb,
    const float* __restrict__ Wg, const float* __restrict__ bg,
    float* __restrict__ co, float* __restrict__ no_)
{
  __shared__ float sCo[4][C_], sNo[4][C_];
  int w = threadIdx.x >> 6, lane = threadIdx.x & 63;
  int gw = blockIdx.x*4 + w;            // row over B*T*N
  int bt = gw >> 10, m = gw & (N_-1);
  int t = bt & (T_-1);
  const int* dv = &divided[(size_t)gw*3];
  int d0=dv[0], d1=dv[1], d2=dv[2];
  bool needCo = (d0|d1|d2) > 0;                 // read by attn (m23) or GRU (m1)
  bool needNo = (t < T_-1) && (divided[((size_t)(gw+N_))*3+1] > 0); // read as q-source at t+1
  if (!needCo && !needNo) return;               // wave-uniform (wave == row)
  float cxm = code_x[gw], nbm = neighbors[gw];
  float acc = 0.f;
  bool needAcc = (needCo && cxm!=0.f) || (needNo && nbm!=0.f);
  if (needAcc){
    int s = rowptr[m], e = rowptr[m+1];
    if (s > NNZ_CAP) s = NNZ_CAP;
    if (e > NNZ_CAP) e = NNZ_CAP;
    int btN = bt << 10;
    for (int base = s; base < e; base += 64){
      int j = base + lane;
      int cc = 0; float wx = 0.f, wy = 0.f;
      if (j < e){
        cc = ccol[j];
        float cv = cval[j];
        float xs = code_x[btN+cc], ys = neighbors[btN+cc];
        wx = cv*xs; wy = cv*ys;
      }
      unsigned long long mk = __ballot(wx!=0.f || wy!=0.f);
      while (mk){
        int u0 = __builtin_ctzll(mk); mk &= (mk-1ULL);
        int u1 = -1;
        if (mk){ u1 = __builtin_ctzll(mk); mk &= (mk-1ULL); }
        int u1s = (u1>=0)? u1 : u0;
        int n0 = __shfl(cc,u0); float a0x=__shfl(wx,u0), a0y=__shfl(wy,u0);
        int n1 = __shfl(cc,u1s); float a1x=__shfl(wx,u1s), a1y=__shfl(wy,u1s);
        float ce0=0.f,ne0=0.f,ce1=0.f,ne1=0.f;
        if (lane < C_){
          ce0 = c_emb[(size_t)n0*C_+lane]; ne0 = n_emb[(size_t)n0*C_+lane];
          ce1 = c_emb[(size_t)n1*C_+lane]; ne1 = n_emb[(size_t)n1*C_+lane];
        }
        acc = fmaf(a0x, ce0, acc); acc = fmaf(a0y, ne0, acc);
        if (u1>=0){ acc = fmaf(a1x, ce1, acc); acc = fmaf(a1y, ne1, acc); }
      }
    }
  }
  if (lane < C_){
    sCo[w][lane] = cxm * (c_emb[(size_t)m*C_+lane] + acc);
    sNo[w][lane] = nbm * (n_emb[(size_t)m*C_+lane] + acc);
  }
  asm volatile("s_waitcnt lgkmcnt(0)" ::: "memory");   // wave-local LDS fence
  int g = lane & 31; bool isNo = lane >= 32;
  const float* src = isNo ? sNo[w] : sCo[w];
  float a2 = bg[g];
  #pragma unroll
  for (int c=0;c<C_;++c) a2 = fmaf(src[c], Wg[c*G_+g], a2);
  float r = a2 >= 0.f ? a2 : 0.01f*a2;
  if (isNo ? needNo : needCo){
    float* dst = isNo ? no_ : co;
    dst[(size_t)gw*G_ + g] = r;
  }
}

// ---------------- attention: one block per (b,t>=1), thread-per-row, LDS broadcast ----------------
__global__ __launch_bounds__(384) void k_attn(
    const float* __restrict__ co, const float* __restrict__ no_,
    const float* __restrict__ u_emb, const int* __restrict__ divided,
    const int* __restrict__ lst23, const int* __restrict__ cnt23, const int* __restrict__ pos1,
    const float* __restrict__ Md, const float* __restrict__ Wv, const float* __restrict__ bv,
    float* __restrict__ hsel, float* __restrict__ om23f)
{
  int b = blockIdx.x; int t = blockIdx.y + 1; int bt = b*T_ + t;
  int cnt = cnt23[bt]; if (cnt > CAP23) cnt = CAP23;
  if (cnt == 0) return;
  __shared__ int   sLst[CAP23];
  __shared__ __align__(16) float sCo[CAP23][G_];   // 48KB
  __shared__ __align__(16) float sW[G_*H_ + H_ + 8];
  __shared__ unsigned sMax[H_];
  int tid = threadIdx.x; int lane = tid & 63;
  for (int i=tid; i<cnt; i+=384) sLst[i] = lst23[(size_t)bt*N_+i];
  for (int i=tid; i<1056; i+=384) sW[i] = Md[i];
  unsigned sent = fenc(-1e30f);
  for (int i=tid; i<H_; i+=384) sMax[i] = sent;
  __syncthreads();
  for (int i=tid; i<cnt*8; i+=384){
    int rrow = i>>3, seg = i&7;
    float4 v = *(const float4*)&co[((((size_t)bt<<10) + sLst[rrow])<<5) + seg*4];
    *(float4*)&sCo[rrow][seg*4] = v;
  }
  bool act = (tid < cnt);
  int n = 0;
  float qpp[G_];
  if (act){
    n = sLst[tid];
    int d1 = divided[((size_t)bt*N_+n)*3+1];
    const float* qsrc = (d1>0) ? &no_[((((size_t)(bt-1))<<10)+n)<<5] : &u_emb[(size_t)n*G_];
    float4 qv[8];
    #pragma unroll
    for (int j=0;j<8;++j) qv[j] = ((const float4*)qsrc)[j];
    #pragma unroll
    for (int j=0;j<G_;++j) qpp[j] = sW[1024+j];
    #pragma unroll
    for (int g=0; g<G_; ++g){
      float qfg = (g&3)==0 ? qv[g>>2].x : (g&3)==1 ? qv[g>>2].y : (g&3)==2 ? qv[g>>2].z : qv[g>>2].w;
      const float4* mr = (const float4*)&sW[g*G_];
      #pragma unroll
      for (int j=0;j<8;++j){
        float4 mj = mr[j];
        qpp[4*j+0] = fmaf(qfg, mj.x, qpp[4*j+0]);
        qpp[4*j+1] = fmaf(qfg, mj.y, qpp[4*j+1]);
        qpp[4*j+2] = fmaf(qfg, mj.z, qpp[4*j+2]);
        qpp[4*j+3] = fmaf(qfg, mj.w, qpp[4*j+3]);
      }
    }
  } else {
    #pragma unroll
    for (int j=0;j<G_;++j) qpp[j]=0.f;
  }
  __syncthreads();
  for (int i=tid; i<G_*H_; i+=384){
    int h=i>>5, g=i&31;
    sW[h*G_+g] = Wv[(size_t)g*H_+h];
  }
  for (int i=tid; i<H_; i+=384) sW[G_*H_+i] = bv[i];
  float pbar[G_]; float l = 0.f;
  #pragma unroll
  for (int j=0;j<G_;++j) pbar[j]=0.f;
  if (act){
    #pragma unroll 2
    for (int c=0;c<cnt;++c){
      const float4* col = (const float4*)&sCo[c][0];
      float4 xv[8];
      #pragma unroll
      for (int j=0;j<8;++j) xv[j]=col[j];
      float d0=0.f,d1v=0.f,d2v=0.f,d3=0.f;
      #pragma unroll
      for (int j=0;j<8;j+=4){
        d0 = fmaf(qpp[4*j+0], xv[j].x, d0); d1v = fmaf(qpp[4*j+1], xv[j].y, d1v);
        d2v = fmaf(qpp[4*j+2], xv[j].z, d2v); d3 = fmaf(qpp[4*j+3], xv[j].w, d3);
        d0 = fmaf(qpp[4*j+4], xv[j+1].x, d0); d1v = fmaf(qpp[4*j+5], xv[j+1].y, d1v);
        d2v = fmaf(qpp[4*j+6], xv[j+1].z, d2v); d3 = fmaf(qpp[4*j+7], xv[j+1].w, d3);
        d0 = fmaf(qpp[4*j+8], xv[j+2].x, d0); d1v = fmaf(qpp[4*j+9], xv[j+2].y, d1v);
        d2v = fmaf(qpp[4*j+10], xv[j+2].z, d2v); d3 = fmaf(qpp[4*j+11], xv[j+2].w, d3);
        d0 = fmaf(qpp[4*j+12], xv[j+3].x, d0); d1v = fmaf(qpp[4*j+13], xv[j+3].y, d1v);
        d2v = fmaf(qpp[4*j+14], xv[j+3].z, d2v); d3 = fmaf(qpp[4*j+15], xv[j+3].w, d3);
      }
      float dot = (d0+d1v)+(d2v+d3);
      float pv = __expf(dot*SCALE_);
      l += pv;
      #pragma unroll
      for (int j=0;j<8;++j){
        pbar[4*j+0] = fmaf(pv, xv[j].x, pbar[4*j+0]);
        pbar[4*j+1] = fmaf(pv, xv[j].y, pbar[4*j+1]);
        pbar[4*j+2] = fmaf(pv, xv[j].z, pbar[4*j+2]);
        pbar[4*j+3] = fmaf(pv, xv[j].w, pbar[4*j+3]);
      }
    }
  }
  if (!act) l = 1.f;
  float inv = 1.f/l;
  #pragma unroll
  for (int j=0;j<G_;++j) pbar[j]*=inv;
  __syncthreads();
  bool wsel=false; float* hd=nullptr;
  if (act && t+1 < T_){
    size_t nidx = ((size_t)b*T_+(t+1))*N_ + n;
    if (divided[nidx*3+0] > 0){
      int pos = pos1[nidx];
      if (pos >= 0 && pos < CAP1){ wsel=true; hd=&hsel[(((size_t)b*T_+t)*CAP1 + pos)*H_]; }
    }
  }
  for (int h=0; h<H_; ++h){
    float acc = sW[G_*H_+h];
    const float4* wv = (const float4*)&sW[h*G_];
    #pragma unroll
    for (int j=0;j<8;++j){
      float4 wj = wv[j];
      acc = fmaf(pbar[4*j+0], wj.x, acc);
      acc = fmaf(pbar[4*j+1], wj.y, acc);
      acc = fmaf(pbar[4*j+2], wj.z, acc);
      acc = fmaf(pbar[4*j+3], wj.w, acc);
    }
    float o = act ? tanhf(acc) : -1e30f;
    float om = wmaxf(o);
    if (lane==0) atomicMax(&sMax[h], fenc(om));
    if (wsel) hd[h] = o;
  }
  __syncthreads();
  for (int i=tid; i<H_; i+=384) om23f[(size_t)bt*H_+i] = fdec(sMax[i]);
}

// ---------------- GRU chain HEADS: 16 chains/block, phase-split GEMMs (no spills) ----------------
__global__ __launch_bounds__(256) void k_gruhead(
    const float* __restrict__ co, const float* __restrict__ hsel,
    const int* __restrict__ divided, const int* __restrict__ pos1,
    const unsigned* __restrict__ chains, const int* __restrict__ nch,
    const float* __restrict__ WihT, const float* __restrict__ b_ih,
    const float* __restrict__ WhhT, const float* __restrict__ b_hh,
    float* __restrict__ gout)
{
  __shared__ float sCo[16][G_];    // 2KB
  __shared__ float sH[16][152];    // 9.73KB (zeroed; h_prev for active slots)
  __shared__ float sG[16][452];    // 28.93KB (phaseA: ih gates; phaseB adds hh to r,z)
  __shared__ float sGhn[16][152];  // 9.73KB (hh n-gate; only written for slot groups < na)
  __shared__ int tBt[16], tN[16], tPos[16], tF[16], tHoff[16], sSlot[16];
  __shared__ int sBt[16], sPos[16];
  __shared__ int sNa;
  int tid = threadIdx.x;
  int NC = *nch; if (NC > CHCAP) NC = CHCAP;
  int base = blockIdx.x * 16;
  if (base >= NC) return;
  int num = min(16, NC - base);
  if (tid < num){
    unsigned cl = chains[base+tid];
    int b = cl>>18, n = (cl>>8)&1023, t0 = (cl>>4)&15;
    int bt = b*T_ + t0;
    int pos = pos1[(size_t)bt*N_ + n];
    int f = 0, hoff = 0;
    if (t0 >= 2 && pos >= 0 && pos < CAP1){
      size_t pidx = ((size_t)(bt-1)*N_ + n)*3;
      if ((divided[pidx+1] | divided[pidx+2]) > 0){
        f = 1; hoff = (b*T_ + (t0-1))*CAP1 + pos;
      }
    }
    tBt[tid]=bt; tN[tid]=n; tPos[tid]=pos; tF[tid]=f; tHoff[tid]=hoff;
  }
  __syncthreads();
  if (tid == 0){
    int lo = 0, hi = num-1;
    for (int i=0;i<num;++i) sSlot[i] = tF[i] ? lo++ : hi--;
    sNa = lo;
  }
  __syncthreads();
  if (tid < num){
    int s = sSlot[tid];
    sBt[s]=tBt[tid]; sPos[s]=tPos[tid];
  }
  for (int i=tid; i<16*152; i+=256) (&sH[0][0])[i] = 0.f;
  __syncthreads();
  // cooperative gathers
  for (int i=tid; i<num*G_; i+=256){
    int ii = i>>5, g = i&31;
    sCo[sSlot[ii]][g] = co[((size_t)tBt[ii]*N_ + tN[ii])*G_ + g];
  }
  for (int i=tid; i<num*152; i+=256){
    int ii = i/152, q = i - ii*152;
    if (tF[ii] && q < H_)
      sH[sSlot[ii]][q] = hsel[(size_t)tHoff[ii]*H_ + q];
  }
  __syncthreads();
  int na = sNa;
  // ---- Phase A: ih-GEMM, acc[16] -> sG (same-thread LDS, no barrier needed) ----
  for (int pass=0; pass<2; ++pass){
    int k = pass*256 + tid;
    if (k < H3_){
      float acc[16];
      #pragma unroll
      for (int u=0;u<16;++u) acc[u]=0.f;
      for (int g=0; g<G_; ++g){
        float wih = WihT[g*H3_ + k];
        #pragma unroll
        for (int u=0;u<16;++u) acc[u] = fmaf(wih, sCo[u][g], acc[u]);
      }
      #pragma unroll
      for (int u=0;u<16;++u) sG[u][k] = acc[u];
    }
  }
  // ---- Phase B: hh-GEMM per 4-slot group, g4[4] live only ----
  for (int pass=0; pass<2; ++pass){
    int k = pass*256 + tid;
    if (k < H3_){
      for (int ug=0; ug<4; ++ug){
        if (ug*4 < na){
          float g4[4] = {0.f,0.f,0.f,0.f};
          for (int q=0; q<H_; ++q){
            float whh = WhhT[q*H3_ + k];
            #pragma unroll
            for (int v=0;v<4;++v) g4[v] = fmaf(whh, sH[ug*4+v][q], g4[v]);
          }
          if (k < 2*H_){
            #pragma unroll
            for (int v=0;v<4;++v) sG[ug*4+v][k] += g4[v];
          } else {
            #pragma unroll
            for (int v=0;v<4;++v) sGhn[ug*4+v][k-2*H_] = g4[v];
          }
        }
      }
    }
  }
  __syncthreads();
  // ---- elementwise GRU combine -> gout (sH zeroed handles no-h; guard unwritten sGhn) ----
  for (int i=tid; i<num*152; i+=256){
    int s = i/152, h = i - s*152;
    if (h < H_){
      int pos = sPos[s];
      if (pos >= 0 && pos < CAP1){
        float ghn = (s < na) ? sGhn[s][h] : 0.f;
        float r = sigmf(sG[s][h]       + b_ih[h]       + b_hh[h]);
        float z = sigmf(sG[s][h+H_]    + b_ih[h+H_]    + b_hh[h+H_]);
        float cand = tanhf(sG[s][h+2*H_] + b_ih[h+2*H_] + r*(ghn + b_hh[h+2*H_]));
        float o = (1.f-z)*cand + z*sH[s][h];
        gout[((size_t)sBt[s]*CAP1 + pos)*H_ + h] = o;
      }
    }
  }
}

// ---------------- GRU chain TAILS (len>=2): serial walk s=1.., 4 chains/wave ----------------
__global__ __launch_bounds__(256) void k_grutail(
    const float* __restrict__ co, const int* __restrict__ pos1,
    const unsigned* __restrict__ chainsL, const int* __restrict__ nchL,
    const float* __restrict__ WihT, const float* __restrict__ b_ih,
    const float* __restrict__ WhhT, const float* __restrict__ b_hh,
    float* __restrict__ gout)
{
  __shared__ float hst[4][4][H_];   // 9.6KB
  int w = threadIdx.x >> 6, lane = threadIdx.x & 63;
  int NC = *nchL; if (NC > CHCAPL) NC = CHCAPL;
  int cbase = (blockIdx.x*4 + w)*4;
  if (cbase >= NC) return;

  int cbv[4], cnv[4], t0v[4], lenv[4];
  #pragma unroll
  for (int u=0;u<4;++u){
    int cid = cbase+u; bool ca = cid < NC;
    unsigned cl = chainsL[ca ? cid : (NC-1)];
    cbv[u]=cl>>18; cnv[u]=(cl>>8)&1023; t0v[u]=(cl>>4)&15;
    lenv[u]= ca ? (int)((cl&15)+1) : 1;   // inactive -> len 1 -> no s>=1 steps
  }
  int maxlen = lenv[0];
  #pragma unroll
  for (int u=1;u<4;++u) maxlen = max(maxlen, lenv[u]);

  int h0=lane,h1=lane+64,h2=lane+128; bool has2=(h2<H_); int h2c=has2?h2:0;
  float bi[9], bh[9];
  bi[0]=b_ih[h0]; bi[1]=b_ih[h0+H_]; bi[2]=b_ih[h0+2*H_];
  bi[3]=b_ih[h1]; bi[4]=b_ih[h1+H_]; bi[5]=b_ih[h1+2*H_];
  bi[6]=b_ih[h2c]; bi[7]=b_ih[h2c+H_]; bi[8]=b_ih[h2c+2*H_];
  bh[0]=b_hh[h0]; bh[1]=b_hh[h0+H_]; bh[2]=b_hh[h0+2*H_];
  bh[3]=b_hh[h1]; bh[4]=b_hh[h1+H_]; bh[5]=b_hh[h1+2*H_];
  bh[6]=b_hh[h2c]; bh[7]=b_hh[h2c+H_]; bh[8]=b_hh[h2c+2*H_];

  for (int s=1; s<maxlen; ++s){
    bool as[4]; int btv[4];
    const float* hp[4];
    #pragma unroll
    for (int u=0;u<4;++u){
      as[u] = s < lenv[u];
      int t = t0v[u] + (as[u] ? s : 0);
      btv[u] = cbv[u]*T_ + t;
      if (s == 1 && as[u]){
        int btp = btv[u] - 1;
        int posp = pos1[(size_t)btp*N_ + cnv[u]];
        if (posp < 0 || posp >= CAP1) posp = 0;
        hp[u] = &gout[((size_t)btp*CAP1 + posp)*H_];
      } else {
        hp[u] = &hst[w][u][0];
      }
    }
    float gi[4][9], gh[4][9];
    #pragma unroll
    for (int u=0;u<4;++u){
      #pragma unroll
      for (int j=0;j<9;++j){ gi[u][j]=bi[j]; gh[u][j]=bh[j]; }
    }
    const float* cop[4];
    #pragma unroll
    for (int u=0;u<4;++u) cop[u] = &co[((size_t)btv[u]*N_ + cnv[u])*G_];
    for (int g=0; g<G_; ++g){
      const float* wr = &WihT[g*H3_];
      float wv[9];
      wv[0]=wr[h0]; wv[1]=wr[h0+H_]; wv[2]=wr[h0+2*H_];
      wv[3]=wr[h1]; wv[4]=wr[h1+H_]; wv[5]=wr[h1+2*H_];
      wv[6]=wr[h2c]; wv[7]=wr[h2c+H_]; wv[8]=wr[h2c+2*H_];
      #pragma unroll
      for (int u=0;u<4;++u){
        float cg = cop[u][g];
        #pragma unroll
        for (int j=0;j<9;++j) gi[u][j]=fmaf(cg, wv[j], gi[u][j]);
      }
    }
    for (int q=0;q<H_;++q){
      const float* wr=&WhhT[q*H3_];
      float wv[9];
      wv[0]=wr[h0]; wv[1]=wr[h0+H_]; wv[2]=wr[h0+2*H_];
      wv[3]=wr[h1]; wv[4]=wr[h1+H_]; wv[5]=wr[h1+2*H_];
      wv[6]=wr[h2c]; wv[7]=wr[h2c+H_]; wv[8]=wr[h2c+2*H_];
      #pragma unroll
      for (int u=0;u<4;++u){
        float hv = hp[u][q];
        #pragma unroll
        for (int j=0;j<9;++j) gh[u][j]=fmaf(hv, wv[j], gh[u][j]);
      }
    }
    #pragma unroll
    for (int u=0;u<4;++u){
      if (as[u]){
        float hv0 = hp[u][h0];
        float hv1 = hp[u][h1];
        float hv2 = has2 ? hp[u][h2] : 0.f;
        float r0=sigmf(gi[u][0]+gh[u][0]), z0=sigmf(gi[u][1]+gh[u][1]);
        float cd0=tanhf(gi[u][2]+r0*gh[u][2]);
        float o0=(1.f-z0)*cd0 + z0*hv0;
        float r1=sigmf(gi[u][3]+gh[u][3]), z1=sigmf(gi[u][4]+gh[u][4]);
        float cd1=tanhf(gi[u][5]+r1*gh[u][5]);
        float o1=(1.f-z1)*cd1 + z1*hv1;
        float o2=0.f;
        if (has2){
          float r2=sigmf(gi[u][6]+gh[u][6]), z2=sigmf(gi[u][7]+gh[u][7]);
          float cd2=tanhf(gi[u][8]+r2*gh[u][8]);
          o2=(1.f-z2)*cd2 + z2*hv2;
        }
        float* hd = &hst[w][u][0];
        hd[h0]=o0; hd[h1]=o1; if (has2) hd[h2]=o2;
        int pos = pos1[(size_t)btv[u]*N_ + cnv[u]];
        if (pos >= 0 && pos < CAP1){
          float* gd = &gout[((size_t)btv[u]*CAP1 + pos)*H_];
          gd[h0]=o0; gd[h1]=o1; if (has2) gd[h2]=o2;
        }
      }
    }
    asm volatile("s_waitcnt lgkmcnt(0)" ::: "memory");  // h stores visible before next s reads
  }
}

// ---------------- per-(b,t) max over m1 rows -> om1f ----------------
__global__ __launch_bounds__(256) void k_om1(
    const float* __restrict__ gout, const int* __restrict__ cnt1, float* __restrict__ om1f)
{
  int bt = blockIdx.x; int tid = threadIdx.x;
  int c1 = cnt1[bt]; if (c1 > CAP1) c1 = CAP1;
  if (tid < H_){
    float mx = -1e30f;
    for (int r=0;r<c1;++r) mx = fmaxf(mx, gout[((size_t)bt*CAP1+r)*H_+tid]);
    om1f[(size_t)bt*H_+tid] = (c1>0) ? mx : 0.f;
  }
}

// ---------------- final: outs assembly, pooling, output ----------------
__global__ __launch_bounds__(256) void k_final(
    const float* __restrict__ om1f, const float* __restrict__ om23f,
    const float* __restrict__ Wp, const float* __restrict__ bp,
    const float* __restrict__ ctx, const float* __restrict__ Wc, const float* __restrict__ bc,
    const int* __restrict__ lens, float* __restrict__ out)
{
  int b = blockIdx.x; int tid = threadIdx.x;
  __shared__ float sOut[T_][H_];
  __shared__ float sTP[T_][P_];
  __shared__ float sVu[T_], sSc[T_], sPool[H_];
  __shared__ float sRed[256];
  for (int i=tid; i<T_*H_; i+=256){
    int t=i/H_, h=i-t*H_;
    float o1 = om1f[((size_t)b*T_+t)*H_+h];
    float o2 = (t>0)? om23f[((size_t)b*T_+t)*H_+h] : 0.f;
    sOut[t][h]=o1+o2;
  }
  __syncthreads();
  for (int pr = tid; pr < T_*P_; pr += 256){
    int t = pr / P_, p = pr - t*P_;
    float acc = bp[p];
    for (int h=0;h<H_;++h) acc = fmaf(sOut[t][h], Wp[h*P_+p], acc);
    sTP[t][p] = acc * ctx[p];
  }
  __syncthreads();
  if (tid < T_){
    float v=0.f;
    for (int p=0;p<P_;++p) v += sTP[tid][p];
    sVu[tid]=v;
  }
  __syncthreads();
  if (tid==0){
    int L = lens[b]; if (L<1) L=1; if (L>T_) L=T_;
    float mx=-1e30f;
    for (int t=0;t<L;++t) mx = fmaxf(mx, sVu[t]);
    float s=0.f;
    for (int t=0;t<L;++t){ float e=__expf(sVu[t]-mx); sSc[t]=e; s+=e; }
    float inv=1.f/s;
    for (int t=0;t<T_;++t) sSc[t] = (t<L)? sSc[t]*inv : 0.f;
  }
  __syncthreads();
  if (tid < H_){
    float acc=0.f;
    for (int t=0;t<T_;++t) acc = fmaf(sOut[t][tid], sSc[t], acc);
    sPool[tid]=acc;
  }
  __syncthreads();
  float v = (tid<H_)? sPool[tid]*Wc[tid] : 0.f;
  sRed[tid]=v; __syncthreads();
  for (int s=128;s>0;s>>=1){ if (tid<s) sRed[tid]+=sRed[tid+s]; __syncthreads(); }
  if (tid==0) out[b] = sRed[0] + bc[0];
}

extern "C" void kernel_launch(void* const* d_in, const int* in_sizes, int n_in,
                              void* d_out, int out_size, void* d_ws, size_t ws_size,
                              hipStream_t stream)
{
  const float* code_x=(const float*)d_in[0];
  const int*   divided=(const int*)d_in[1];
  const float* neighbors=(const float*)d_in[2];
  const int*   lens=(const int*)d_in[3];
  const float* prior=(const float*)d_in[4];
  const float* adj=(const float*)d_in[5];
  const float* c_emb=(const float*)d_in[6];
  const float* n_emb=(const float*)d_in[7];
  const float* u_emb=(const float*)d_in[8];
  const float* Wg=(const float*)d_in[9];
  const float* bg=(const float*)d_in[10];
  const float* W_ih=(const float*)d_in[11];
  const float* b_ih=(const float*)d_in[12];
  const float* W_hh=(const float*)d_in[13];
  const float* b_hh=(const float*)d_in[14];
  const float* Wq=(const float*)d_in[15];
  const float* bq=(const float*)d_in[16];
  const float* Wk=(const float*)d_in[17];
  const float* bk=(const float*)d_in[18];
  const float* Wv=(const float*)d_in[19];
  const float* bv=(const float*)d_in[20];
  const float* Wp=(const float*)d_in[21];
  const float* bp=(const float*)d_in[22];
  const float* ctx=(const float*)d_in[23];
  const float* Wc=(const float*)d_in[24];
  const float* bc=(const float*)d_in[25];
  float* out=(float*)d_out;
  (void)in_sizes; (void)n_in; (void)out_size; (void)ws_size; (void)bk;

  char* p=(char*)d_ws;
  size_t off=0;
  auto carve=[&](size_t bytes)->char*{ char* r=p+off; off=(off+bytes+255)&~(size_t)255; return r; };
  int*   rowptr=(int*)carve((N_+1)*4);
  int*   rcnt  =(int*)carve(N_*4);
  int*   ccol  =(int*)carve((size_t)NNZ_CAP*4);
  float* cval  =(float*)carve((size_t)NNZ_CAP*4);
  int*   cnt23 =(int*)carve(B_*T_*4);
  int*   cnt1  =(int*)carve(B_*T_*4);
  int*   lst23 =(int*)carve((size_t)B_*T_*N_*4);
  int*   pos1  =(int*)carve((size_t)B_*T_*N_*4);
  float* co    =(float*)carve((size_t)B_*T_*N_*G_*4);
  float* no_   =(float*)carve((size_t)B_*T_*N_*G_*4);
  float* WihT  =(float*)carve((size_t)G_*H3_*4);
  float* WhhT  =(float*)carve((size_t)H_*H3_*4);
  float* Md    =(float*)carve(1056*4);
  float* hsel  =(float*)carve((size_t)B_*T_*CAP1*H_*4);
  float* gout  =(float*)carve((size_t)B_*T_*CAP1*H_*4);
  unsigned* chains=(unsigned*)carve((size_t)CHCAP*4);
  unsigned* chainsL=(unsigned*)carve((size_t)CHCAPL*4);
  int*   nch   =(int*)carve(256);
  int*   nchL  =(int*)carve(256);
  float* om1f  =(float*)carve((size_t)B_*T_*H_*4);
  float* om23f =(float*)carve((size_t)B_*T_*H_*4);

  k_csr_cnt<<<N_,256,0,stream>>>(adj, rcnt);
  k_csr_scan<<<1,64,0,stream>>>(rcnt, rowptr);
  k_csr_fill<<<N_,64,0,stream>>>(adj, prior, rowptr, ccol, cval);
  k_masks<<<B_*T_,64,0,stream>>>(divided, lst23, pos1, cnt23, cnt1);
  k_wt<<<325,256,0,stream>>>(W_ih, W_hh, Wq, bq, Wk, WihT, WhhT, Md);
  k_init<<<(B_*T_*H_+255)/256,256,0,stream>>>(om23f, nch, nchL);
  k_chains<<<(B_*N_+255)/256,256,0,stream>>>(divided, chains, nch, chainsL, nchL);
  k_cono<<<B_*T_*N_/4,256,0,stream>>>(code_x, neighbors, divided, rowptr, ccol, cval,
                                      c_emb, n_emb, Wg, bg, co, no_);
  k_attn<<<dim3(B_, T_-1),384,0,stream>>>(co, no_, u_emb, divided,
                                      lst23, cnt23, pos1, Md, Wv, bv,
                                      hsel, om23f);
  k_gruhead<<<CHCAP/16,256,0,stream>>>(co, hsel, divided, pos1, chains, nch,
                                      WihT, b_ih, WhhT, b_hh, gout);
  k_grutail<<<CHCAPL/16,256,0,stream>>>(co, pos1, chainsL, nchL,
                                      WihT, b_ih, WhhT, b_hh, gout);
  k_om1<<<B_*T_,256,0,stream>>>(gout, cnt1, om1f);
  k_final<<<B_,256,0,stream>>>(om1f, om23f, Wp,bp,ctx,Wc,bc, lens, out);
}

// Round 9
// 525.687 us; speedup vs baseline: 2.2818x; 1.3315x over previous
//
#include <hip/hip_runtime.h>

#define B_ 16
#define T_ 16
#define N_ 1024
#define C_ 48
#define G_ 32
#define H_ 150
#define A_ 32
#define P_ 32
#define H3_ 450
#define NNZ_CAP 262144
#define CAP1 256
#define CAP23 384
#define CHCAP 40960
#define CHCAPL 16384
#define SCALE_ 0.17677669529663687f

__device__ __forceinline__ unsigned fenc(float f){
  unsigned u = __float_as_uint(f);
  return (u & 0x80000000u) ? ~u : (u | 0x80000000u);
}
__device__ __forceinline__ float fdec(unsigned e){
  unsigned u = (e & 0x80000000u) ? (e & 0x7fffffffu) : ~e;
  return __uint_as_float(u);
}
__device__ __forceinline__ float sigmf(float x){ return 1.f/(1.f+__expf(-x)); }
__device__ __forceinline__ float wmaxf(float v){
  #pragma unroll
  for (int d=32; d>0; d>>=1) v = fmaxf(v, __shfl_xor(v,d));
  return v;
}

#define FMA16(W, PTR, ACC) do { \
    const float4* _c4 = (const float4*)(PTR); \
    float4 _c0=_c4[0], _c1=_c4[1], _c2=_c4[2], _c3=_c4[3]; \
    ACC[0]=fmaf((W),_c0.x,ACC[0]); ACC[1]=fmaf((W),_c0.y,ACC[1]); \
    ACC[2]=fmaf((W),_c0.z,ACC[2]); ACC[3]=fmaf((W),_c0.w,ACC[3]); \
    ACC[4]=fmaf((W),_c1.x,ACC[4]); ACC[5]=fmaf((W),_c1.y,ACC[5]); \
    ACC[6]=fmaf((W),_c1.z,ACC[6]); ACC[7]=fmaf((W),_c1.w,ACC[7]); \
    ACC[8]=fmaf((W),_c2.x,ACC[8]); ACC[9]=fmaf((W),_c2.y,ACC[9]); \
    ACC[10]=fmaf((W),_c2.z,ACC[10]); ACC[11]=fmaf((W),_c2.w,ACC[11]); \
    ACC[12]=fmaf((W),_c3.x,ACC[12]); ACC[13]=fmaf((W),_c3.y,ACC[13]); \
    ACC[14]=fmaf((W),_c3.z,ACC[14]); ACC[15]=fmaf((W),_c3.w,ACC[15]); \
  } while(0)

// ---------------- CSR build for adj (5% dense), prior folded into cval ----------------
__global__ void k_csr_cnt(const float* __restrict__ adj, int* __restrict__ rcnt){
  int m = blockIdx.x; int tid = threadIdx.x;
  int c = 0;
  for (int n = tid; n < N_; n += 256) c += (adj[(size_t)m*N_+n] != 0.f) ? 1 : 0;
  __shared__ int sr[256];
  sr[tid]=c; __syncthreads();
  for (int s=128; s>0; s>>=1){ if (tid<s) sr[tid]+=sr[tid+s]; __syncthreads(); }
  if (tid==0) rcnt[m]=sr[0];
}
__global__ void k_csr_scan(const int* __restrict__ rcnt, int* __restrict__ rowptr){
  int lane = threadIdx.x; // 64 threads
  int s = 0;
  for (int r=0;r<16;++r) s += rcnt[lane*16+r];
  int incl = s;
  for (int d=1; d<64; d<<=1){ int y = __shfl_up(incl, d); if (lane>=d) incl += y; }
  int run = incl - s;
  for (int r=0;r<16;++r){ rowptr[lane*16+r] = run; run += rcnt[lane*16+r]; }
  if (lane==63) rowptr[N_] = incl;
}
__global__ void k_csr_fill(const float* __restrict__ adj, const float* __restrict__ prior,
                           const int* __restrict__ rowptr,
                           int* __restrict__ ccol, float* __restrict__ cval){
  int m = blockIdx.x; int lane = threadIdx.x; // 64
  int base = rowptr[m];
  float pm = prior[m];
  for (int it=0; it<N_/64; ++it){
    int n = it*64+lane;
    float a = adj[(size_t)m*N_+n];
    bool pnz = (a != 0.f);
    unsigned long long mk = __ballot(pnz);
    if (pnz){
      int idx = base + __popcll(mk & ((1ULL<<lane)-1ULL));
      if (idx < NNZ_CAP){ ccol[idx]=n; cval[idx]=a*pm; }
    }
    base += __popcll(mk);
  }
}

// ---------------- mask compaction: lst23 + pos1 + counts ----------------
__global__ void k_masks(const int* __restrict__ divided, int* __restrict__ lst23,
                        int* __restrict__ pos1,
                        int* __restrict__ cnt23, int* __restrict__ cnt1){
  int bt = blockIdx.x; int lane = threadIdx.x; // 64
  int base23=0, base1=0;
  for (int it=0; it<N_/64; ++it){
    int n = it*64+lane;
    const int* dv = &divided[((size_t)bt*N_+n)*3];
    int d0=dv[0], d1=dv[1], d2=dv[2];
    bool p23 = (d1>0)||(d2>0); bool p1 = d0>0;
    unsigned long long mk23 = __ballot(p23);
    unsigned long long mk1  = __ballot(p1);
    unsigned long long ltm = (1ULL<<lane)-1ULL;
    if (p23){ int idx = base23 + __popcll(mk23 & ltm); lst23[(size_t)bt*N_+idx]=n; }
    if (p1){ int idx = base1 + __popcll(mk1 & ltm); pos1[(size_t)bt*N_+n]=idx; }
    base23 += __popcll(mk23); base1 += __popcll(mk1);
  }
  if (lane==0){ cnt23[bt]=base23; cnt1[bt]=base1; }
}

// ---------------- chain extraction: split heads into NoH / H lists; tails (len>=2) ----------------
__global__ void k_chains(const int* __restrict__ divided,
                         unsigned* __restrict__ chN, int* __restrict__ nchN,
                         unsigned* __restrict__ chH, int* __restrict__ nchH,
                         unsigned* __restrict__ chL, int* __restrict__ nchL){
  int idx = blockIdx.x*256 + threadIdx.x;   // over B*N
  if (idx >= B_*N_) return;
  int b = idx >> 10, n = idx & (N_-1);
  unsigned m1m = 0;
  for (int t=0;t<T_;++t){
    int d0 = divided[(((size_t)(b*T_+t))*N_ + n)*3];
    if (d0>0) m1m |= (1u<<t);
  }
  unsigned heads = m1m & ~(m1m<<1);
  while (heads){
    int t0 = __builtin_ctz(heads); heads &= (heads-1u);
    unsigned run = m1m >> t0;
    int len = __builtin_ctz(~run);   // trailing ones = chain length
    unsigned enc = ((unsigned)b<<18)|((unsigned)n<<8)|((unsigned)t0<<4)|(unsigned)(len-1);
    int f = 0;
    if (t0 >= 2){
      size_t pidx = ((size_t)(b*T_+t0-1)*N_ + n)*3;
      if ((divided[pidx+1] | divided[pidx+2]) > 0) f = 1;
    }
    if (f){ int i2 = atomicAdd(nchH,1); if (i2 < CHCAP) chH[i2]=enc; }
    else  { int i2 = atomicAdd(nchN,1); if (i2 < CHCAP) chN[i2]=enc; }
    if (len >= 2){
      int i2 = atomicAdd(nchL, 1);
      if (i2 < CHCAPL) chL[i2] = enc;
    }
  }
}

// ---------------- weight transposes + fused q-projection matrix M = Wq Wk^T, d = Wk bq ----------------
__global__ void k_wt(const float* __restrict__ W_ih, const float* __restrict__ W_hh,
                     const float* __restrict__ Wq, const float* __restrict__ bq,
                     const float* __restrict__ Wk,
                     float* __restrict__ WihT, float* __restrict__ WhhT,
                     float* __restrict__ Md){
  int idx = blockIdx.x*256+threadIdx.x;
  if (idx < G_*H3_){ int g=idx/H3_, k=idx-g*H3_; WihT[g*H3_+k]=W_ih[(size_t)k*G_+g]; }
  int idx2 = idx - G_*H3_;
  if (idx2>=0 && idx2 < H_*H3_){ int h=idx2/H3_, k=idx2-h*H3_; WhhT[h*H3_+k]=W_hh[(size_t)k*H_+h]; }
  int e = idx - (G_*H3_ + H_*H3_);
  if (e>=0 && e<1024){
    int g=e>>5, gp=e&31;
    float acc=0.f;
    #pragma unroll
    for (int a=0;a<A_;++a) acc = fmaf(Wq[g*A_+a], Wk[gp*A_+a], acc);
    Md[e]=acc;
  }
  int e2 = e - 1024;
  if (e2>=0 && e2<32){
    float acc=0.f;
    #pragma unroll
    for (int a=0;a<A_;++a) acc = fmaf(Wk[e2*A_+a], bq[a], acc);
    Md[1024+e2]=acc;
  }
}

__global__ void k_init(float* __restrict__ om23f, int* __restrict__ nchN,
                       int* __restrict__ nchH, int* __restrict__ nchL){
  int i = blockIdx.x*256+threadIdx.x;
  if (i<B_*T_*H_){ om23f[i]=0.f; }
  if (i==0){ *nchN = 0; *nchH = 0; *nchL = 0; }
}

// ---------------- fused agg -> co,no, demand-driven (only rows consumers read) ----------------
__global__ __launch_bounds__(256) void k_cono(
    const float* __restrict__ code_x, const float* __restrict__ neighbors,
    const int* __restrict__ divided,
    const int* __restrict__ rowptr, const int* __restrict__ ccol, const float* __restrict__ cval,
    const float* __restrict__ c_emb, const float* __restrict__ n_emb,
    const float* __restrict__ Wg, const float* __restrict__ bg,
    float* __restrict__ co, float* __restrict__ no_)
{
  __shared__ float sCo[4][C_], sNo[4][C_];
  int w = threadIdx.x >> 6, lane = threadIdx.x & 63;
  int gw = blockIdx.x*4 + w;            // row over B*T*N
  int bt = gw >> 10, m = gw & (N_-1);
  int t = bt & (T_-1);
  const int* dv = &divided[(size_t)gw*3];
  int d0=dv[0], d1=dv[1], d2=dv[2];
  bool needCo = (d0|d1|d2) > 0;                 // read by attn (m23) or GRU (m1)
  bool needNo = (t < T_-1) && (divided[((size_t)(gw+N_))*3+1] > 0); // read as q-source at t+1
  if (!needCo && !needNo) return;               // wave-uniform (wave == row)
  float cxm = code_x[gw], nbm = neighbors[gw];
  float acc = 0.f;
  bool needAcc = (needCo && cxm!=0.f) || (needNo && nbm!=0.f);
  if (needAcc){
    int s = rowptr[m], e = rowptr[m+1];
    if (s > NNZ_CAP) s = NNZ_CAP;
    if (e > NNZ_CAP) e = NNZ_CAP;
    int btN = bt << 10;
    for (int base = s; base < e; base += 64){
      int j = base + lane;
      int cc = 0; float wx = 0.f, wy = 0.f;
      if (j < e){
        cc = ccol[j];
        float cv = cval[j];
        float xs = code_x[btN+cc], ys = neighbors[btN+cc];
        wx = cv*xs; wy = cv*ys;
      }
      unsigned long long mk = __ballot(wx!=0.f || wy!=0.f);
      while (mk){
        int u0 = __builtin_ctzll(mk); mk &= (mk-1ULL);
        int u1 = -1;
        if (mk){ u1 = __builtin_ctzll(mk); mk &= (mk-1ULL); }
        int u1s = (u1>=0)? u1 : u0;
        int n0 = __shfl(cc,u0); float a0x=__shfl(wx,u0), a0y=__shfl(wy,u0);
        int n1 = __shfl(cc,u1s); float a1x=__shfl(wx,u1s), a1y=__shfl(wy,u1s);
        float ce0=0.f,ne0=0.f,ce1=0.f,ne1=0.f;
        if (lane < C_){
          ce0 = c_emb[(size_t)n0*C_+lane]; ne0 = n_emb[(size_t)n0*C_+lane];
          ce1 = c_emb[(size_t)n1*C_+lane]; ne1 = n_emb[(size_t)n1*C_+lane];
        }
        acc = fmaf(a0x, ce0, acc); acc = fmaf(a0y, ne0, acc);
        if (u1>=0){ acc = fmaf(a1x, ce1, acc); acc = fmaf(a1y, ne1, acc); }
      }
    }
  }
  if (lane < C_){
    sCo[w][lane] = cxm * (c_emb[(size_t)m*C_+lane] + acc);
    sNo[w][lane] = nbm * (n_emb[(size_t)m*C_+lane] + acc);
  }
  asm volatile("s_waitcnt lgkmcnt(0)" ::: "memory");   // wave-local LDS fence
  int g = lane & 31; bool isNo = lane >= 32;
  const float* src = isNo ? sNo[w] : sCo[w];
  float a2 = bg[g];
  #pragma unroll
  for (int c=0;c<C_;++c) a2 = fmaf(src[c], Wg[c*G_+g], a2);
  float r = a2 >= 0.f ? a2 : 0.01f*a2;
  if (isNo ? needNo : needCo){
    float* dst = isNo ? no_ : co;
    dst[(size_t)gw*G_ + g] = r;
  }
}

// ---------------- attention: one block per (b,t>=1), thread-per-row, LDS broadcast ----------------
__global__ __launch_bounds__(384) void k_attn(
    const float* __restrict__ co, const float* __restrict__ no_,
    const float* __restrict__ u_emb, const int* __restrict__ divided,
    const int* __restrict__ lst23, const int* __restrict__ cnt23, const int* __restrict__ pos1,
    const float* __restrict__ Md, const float* __restrict__ Wv, const float* __restrict__ bv,
    float* __restrict__ hsel, float* __restrict__ om23f)
{
  int b = blockIdx.x; int t = blockIdx.y + 1; int bt = b*T_ + t;
  int cnt = cnt23[bt]; if (cnt > CAP23) cnt = CAP23;
  if (cnt == 0) return;
  __shared__ int   sLst[CAP23];
  __shared__ __align__(16) float sCo[CAP23][G_];   // 48KB
  __shared__ __align__(16) float sW[G_*H_ + H_ + 8];
  __shared__ unsigned sMax[H_];
  int tid = threadIdx.x; int lane = tid & 63;
  for (int i=tid; i<cnt; i+=384) sLst[i] = lst23[(size_t)bt*N_+i];
  for (int i=tid; i<1056; i+=384) sW[i] = Md[i];
  unsigned sent = fenc(-1e30f);
  for (int i=tid; i<H_; i+=384) sMax[i] = sent;
  __syncthreads();
  for (int i=tid; i<cnt*8; i+=384){
    int rrow = i>>3, seg = i&7;
    float4 v = *(const float4*)&co[((((size_t)bt<<10) + sLst[rrow])<<5) + seg*4];
    *(float4*)&sCo[rrow][seg*4] = v;
  }
  bool act = (tid < cnt);
  int n = 0;
  float qpp[G_];
  if (act){
    n = sLst[tid];
    int d1 = divided[((size_t)bt*N_+n)*3+1];
    const float* qsrc = (d1>0) ? &no_[((((size_t)(bt-1))<<10)+n)<<5] : &u_emb[(size_t)n*G_];
    float4 qv[8];
    #pragma unroll
    for (int j=0;j<8;++j) qv[j] = ((const float4*)qsrc)[j];
    #pragma unroll
    for (int j=0;j<G_;++j) qpp[j] = sW[1024+j];
    #pragma unroll
    for (int g=0; g<G_; ++g){
      float qfg = (g&3)==0 ? qv[g>>2].x : (g&3)==1 ? qv[g>>2].y : (g&3)==2 ? qv[g>>2].z : qv[g>>2].w;
      const float4* mr = (const float4*)&sW[g*G_];
      #pragma unroll
      for (int j=0;j<8;++j){
        float4 mj = mr[j];
        qpp[4*j+0] = fmaf(qfg, mj.x, qpp[4*j+0]);
        qpp[4*j+1] = fmaf(qfg, mj.y, qpp[4*j+1]);
        qpp[4*j+2] = fmaf(qfg, mj.z, qpp[4*j+2]);
        qpp[4*j+3] = fmaf(qfg, mj.w, qpp[4*j+3]);
      }
    }
  } else {
    #pragma unroll
    for (int j=0;j<G_;++j) qpp[j]=0.f;
  }
  __syncthreads();
  for (int i=tid; i<G_*H_; i+=384){
    int h=i>>5, g=i&31;
    sW[h*G_+g] = Wv[(size_t)g*H_+h];
  }
  for (int i=tid; i<H_; i+=384) sW[G_*H_+i] = bv[i];
  float pbar[G_]; float l = 0.f;
  #pragma unroll
  for (int j=0;j<G_;++j) pbar[j]=0.f;
  if (act){
    #pragma unroll 2
    for (int c=0;c<cnt;++c){
      const float4* col = (const float4*)&sCo[c][0];
      float4 xv[8];
      #pragma unroll
      for (int j=0;j<8;++j) xv[j]=col[j];
      float d0=0.f,d1v=0.f,d2v=0.f,d3=0.f;
      #pragma unroll
      for (int j=0;j<8;j+=4){
        d0 = fmaf(qpp[4*j+0], xv[j].x, d0); d1v = fmaf(qpp[4*j+1], xv[j].y, d1v);
        d2v = fmaf(qpp[4*j+2], xv[j].z, d2v); d3 = fmaf(qpp[4*j+3], xv[j].w, d3);
        d0 = fmaf(qpp[4*j+4], xv[j+1].x, d0); d1v = fmaf(qpp[4*j+5], xv[j+1].y, d1v);
        d2v = fmaf(qpp[4*j+6], xv[j+1].z, d2v); d3 = fmaf(qpp[4*j+7], xv[j+1].w, d3);
        d0 = fmaf(qpp[4*j+8], xv[j+2].x, d0); d1v = fmaf(qpp[4*j+9], xv[j+2].y, d1v);
        d2v = fmaf(qpp[4*j+10], xv[j+2].z, d2v); d3 = fmaf(qpp[4*j+11], xv[j+2].w, d3);
        d0 = fmaf(qpp[4*j+12], xv[j+3].x, d0); d1v = fmaf(qpp[4*j+13], xv[j+3].y, d1v);
        d2v = fmaf(qpp[4*j+14], xv[j+3].z, d2v); d3 = fmaf(qpp[4*j+15], xv[j+3].w, d3);
      }
      float dot = (d0+d1v)+(d2v+d3);
      float pv = __expf(dot*SCALE_);
      l += pv;
      #pragma unroll
      for (int j=0;j<8;++j){
        pbar[4*j+0] = fmaf(pv, xv[j].x, pbar[4*j+0]);
        pbar[4*j+1] = fmaf(pv, xv[j].y, pbar[4*j+1]);
        pbar[4*j+2] = fmaf(pv, xv[j].z, pbar[4*j+2]);
        pbar[4*j+3] = fmaf(pv, xv[j].w, pbar[4*j+3]);
      }
    }
  }
  if (!act) l = 1.f;
  float inv = 1.f/l;
  #pragma unroll
  for (int j=0;j<G_;++j) pbar[j]*=inv;
  __syncthreads();
  bool wsel=false; float* hd=nullptr;
  if (act && t+1 < T_){
    size_t nidx = ((size_t)b*T_+(t+1))*N_ + n;
    if (divided[nidx*3+0] > 0){
      int pos = pos1[nidx];
      if (pos >= 0 && pos < CAP1){ wsel=true; hd=&hsel[(((size_t)b*T_+t)*CAP1 + pos)*H_]; }
    }
  }
  for (int h=0; h<H_; ++h){
    float acc = sW[G_*H_+h];
    const float4* wv = (const float4*)&sW[h*G_];
    #pragma unroll
    for (int j=0;j<8;++j){
      float4 wj = wv[j];
      acc = fmaf(pbar[4*j+0], wj.x, acc);
      acc = fmaf(pbar[4*j+1], wj.y, acc);
      acc = fmaf(pbar[4*j+2], wj.z, acc);
      acc = fmaf(pbar[4*j+3], wj.w, acc);
    }
    float o = act ? tanhf(acc) : -1e30f;
    float om = wmaxf(o);
    if (lane==0) atomicMax(&sMax[h], fenc(om));
    if (wsel) hd[h] = o;
  }
  __syncthreads();
  for (int i=tid; i<H_; i+=384) om23f[(size_t)bt*H_+i] = fdec(sMax[i]);
}

// ---------------- GRU heads WITHOUT h_prev: ih-GEMM only, ~31KB LDS ----------------
__global__ __launch_bounds__(256) void k_gruheadN(
    const float* __restrict__ co, const int* __restrict__ pos1,
    const unsigned* __restrict__ chN, const int* __restrict__ nchN,
    const float* __restrict__ WihT, const float* __restrict__ b_ih,
    const float* __restrict__ b_hh, float* __restrict__ gout)
{
  __shared__ __align__(16) float sCoT[G_][16];   // 2KB (transposed)
  __shared__ float sG[16][452];                  // 28.9KB
  __shared__ int sBt[16], sN[16], sPos[16];
  int tid = threadIdx.x;
  int NC = *nchN; if (NC > CHCAP) NC = CHCAP;
  int base = blockIdx.x * 16;
  if (base >= NC) return;
  int num = min(16, NC - base);
  if (tid < 16){
    if (tid < num){
      unsigned cl = chN[base+tid];
      int b = cl>>18, n = (cl>>8)&1023, t0 = (cl>>4)&15;
      int bt = b*T_ + t0;
      sBt[tid]=bt; sN[tid]=n; sPos[tid]=pos1[(size_t)bt*N_+n];
    } else { sBt[tid]=0; sN[tid]=0; sPos[tid]=-1; }
  }
  __syncthreads();
  for (int i=tid; i<G_*16; i+=256){
    int g = i>>4, ii = i&15;
    sCoT[g][ii] = (ii<num) ? co[((size_t)sBt[ii]*N_+sN[ii])*G_+g] : 0.f;
  }
  __syncthreads();
  for (int pass=0; pass<2; ++pass){
    int k = pass*256 + tid;
    if (k < H3_){
      float acc[16];
      #pragma unroll
      for (int u=0;u<16;++u) acc[u]=0.f;
      for (int g=0; g<G_; ++g){
        float wih = WihT[g*H3_ + k];
        FMA16(wih, &sCoT[g][0], acc);
      }
      #pragma unroll
      for (int u=0;u<16;++u) sG[u][k] = acc[u];
    }
  }
  __syncthreads();
  for (int i=tid; i<num*152; i+=256){
    int s = i/152, h = i - s*152;
    if (h < H_){
      int pos = sPos[s];
      if (pos >= 0 && pos < CAP1){
        float r = sigmf(sG[s][h]       + b_ih[h]       + b_hh[h]);
        float z = sigmf(sG[s][h+H_]    + b_ih[h+H_]    + b_hh[h+H_]);
        float cand = tanhf(sG[s][h+2*H_] + b_ih[h+2*H_] + r*b_hh[h+2*H_]);
        gout[((size_t)sBt[s]*CAP1 + pos)*H_ + h] = (1.f-z)*cand;
      }
    }
  }
}

// ---------------- GRU heads WITH h_prev: ih + hh GEMMs, all 16 slots active ----------------
__global__ __launch_bounds__(256) void k_gruheadH(
    const float* __restrict__ co, const float* __restrict__ hsel,
    const int* __restrict__ pos1,
    const unsigned* __restrict__ chH, const int* __restrict__ nchH,
    const float* __restrict__ WihT, const float* __restrict__ b_ih,
    const float* __restrict__ WhhT, const float* __restrict__ b_hh,
    float* __restrict__ gout)
{
  __shared__ __align__(16) float sCoT[G_][16];   // 2KB
  __shared__ __align__(16) float sHT[152][16];   // 9.73KB (transposed h_prev)
  __shared__ float sG[16][452];                  // 28.9KB (r,z: ih+hh; n: ih)
  __shared__ float sGhn[16][152];                // 9.73KB (hh n-gate)
  __shared__ int sBt[16], sN[16], sPos[16], sHo[16];
  int tid = threadIdx.x;
  int NC = *nchH; if (NC > CHCAP) NC = CHCAP;
  int base = blockIdx.x * 16;
  if (base >= NC) return;
  int num = min(16, NC - base);
  if (tid < 16){
    if (tid < num){
      unsigned cl = chH[base+tid];
      int b = cl>>18, n = (cl>>8)&1023, t0 = (cl>>4)&15;
      int bt = b*T_ + t0;
      int pos = pos1[(size_t)bt*N_+n];
      sBt[tid]=bt; sN[tid]=n; sPos[tid]=pos;
      sHo[tid] = (b*T_ + (t0-1))*CAP1 + ((pos>=0 && pos<CAP1) ? pos : 0);
    } else { sBt[tid]=0; sN[tid]=0; sPos[tid]=-1; sHo[tid]=0; }
  }
  __syncthreads();
  for (int i=tid; i<G_*16; i+=256){
    int g = i>>4, ii = i&15;
    sCoT[g][ii] = (ii<num) ? co[((size_t)sBt[ii]*N_+sN[ii])*G_+g] : 0.f;
  }
  for (int i=tid; i<152*16; i+=256){
    int q = i>>4, ii = i&15;
    float v = 0.f;
    if (ii < num && q < H_) v = hsel[(size_t)sHo[ii]*H_ + q];
    sHT[q][ii] = v;
  }
  __syncthreads();
  // Phase A: ih-GEMM
  for (int pass=0; pass<2; ++pass){
    int k = pass*256 + tid;
    if (k < H3_){
      float acc[16];
      #pragma unroll
      for (int u=0;u<16;++u) acc[u]=0.f;
      for (int g=0; g<G_; ++g){
        float wih = WihT[g*H3_ + k];
        FMA16(wih, &sCoT[g][0], acc);
      }
      #pragma unroll
      for (int u=0;u<16;++u) sG[u][k] = acc[u];
    }
  }
  // Phase B: hh-GEMM, WhhT loaded once per (q,k), all 16 slots
  for (int pass=0; pass<2; ++pass){
    int k = pass*256 + tid;
    if (k < H3_){
      float acc[16];
      #pragma unroll
      for (int u=0;u<16;++u) acc[u]=0.f;
      for (int q=0; q<H_; ++q){
        float whh = WhhT[q*H3_ + k];
        FMA16(whh, &sHT[q][0], acc);
      }
      if (k < 2*H_){
        #pragma unroll
        for (int u=0;u<16;++u) sG[u][k] += acc[u];
      } else {
        #pragma unroll
        for (int u=0;u<16;++u) sGhn[u][k-2*H_] = acc[u];
      }
    }
  }
  __syncthreads();
  for (int i=tid; i<num*152; i+=256){
    int s = i/152, h = i - s*152;
    if (h < H_){
      int pos = sPos[s];
      if (pos >= 0 && pos < CAP1){
        float hv = sHT[h][s];
        float r = sigmf(sG[s][h]       + b_ih[h]       + b_hh[h]);
        float z = sigmf(sG[s][h+H_]    + b_ih[h+H_]    + b_hh[h+H_]);
        float cand = tanhf(sG[s][h+2*H_] + b_ih[h+2*H_] + r*(sGhn[s][h] + b_hh[h+2*H_]));
        float o = (1.f-z)*cand + z*hv;
        gout[((size_t)sBt[s]*CAP1 + pos)*H_ + h] = o;
      }
    }
  }
}

// ---------------- GRU chain TAILS (len>=2): serial walk s=1.., 4 chains/wave ----------------
__global__ __launch_bounds__(256) void k_grutail(
    const float* __restrict__ co, const int* __restrict__ pos1,
    const unsigned* __restrict__ chainsL, const int* __restrict__ nchL,
    const float* __restrict__ WihT, const float* __restrict__ b_ih,
    const float* __restrict__ WhhT, const float* __restrict__ b_hh,
    float* __restrict__ gout)
{
  __shared__ float hst[4][4][H_];   // 9.6KB
  int w = threadIdx.x >> 6, lane = threadIdx.x & 63;
  int NC = *nchL; if (NC > CHCAPL) NC = CHCAPL;
  int cbase = (blockIdx.x*4 + w)*4;
  if (cbase >= NC) return;

  int cbv[4], cnv[4], t0v[4], lenv[4];
  #pragma unroll
  for (int u=0;u<4;++u){
    int cid = cbase+u; bool ca = cid < NC;
    unsigned cl = chainsL[ca ? cid : (NC-1)];
    cbv[u]=cl>>18; cnv[u]=(cl>>8)&1023; t0v[u]=(cl>>4)&15;
    lenv[u]= ca ? (int)((cl&15)+1) : 1;   // inactive -> len 1 -> no s>=1 steps
  }
  int maxlen = lenv[0];
  #pragma unroll
  for (int u=1;u<4;++u) maxlen = max(maxlen, lenv[u]);

  int h0=lane,h1=lane+64,h2=lane+128; bool has2=(h2<H_); int h2c=has2?h2:0;
  float bi[9], bh[9];
  bi[0]=b_ih[h0]; bi[1]=b_ih[h0+H_]; bi[2]=b_ih[h0+2*H_];
  bi[3]=b_ih[h1]; bi[4]=b_ih[h1+H_]; bi[5]=b_ih[h1+2*H_];
  bi[6]=b_ih[h2c]; bi[7]=b_ih[h2c+H_]; bi[8]=b_ih[h2c+2*H_];
  bh[0]=b_hh[h0]; bh[1]=b_hh[h0+H_]; bh[2]=b_hh[h0+2*H_];
  bh[3]=b_hh[h1]; bh[4]=b_hh[h1+H_]; bh[5]=b_hh[h1+2*H_];
  bh[6]=b_hh[h2c]; bh[7]=b_hh[h2c+H_]; bh[8]=b_hh[h2c+2*H_];

  for (int s=1; s<maxlen; ++s){
    bool as[4]; int btv[4];
    const float* hp[4];
    #pragma unroll
    for (int u=0;u<4;++u){
      as[u] = s < lenv[u];
      int t = t0v[u] + (as[u] ? s : 0);
      btv[u] = cbv[u]*T_ + t;
      if (s == 1 && as[u]){
        int btp = btv[u] - 1;
        int posp = pos1[(size_t)btp*N_ + cnv[u]];
        if (posp < 0 || posp >= CAP1) posp = 0;
        hp[u] = &gout[((size_t)btp*CAP1 + posp)*H_];
      } else {
        hp[u] = &hst[w][u][0];
      }
    }
    float gi[4][9], gh[4][9];
    #pragma unroll
    for (int u=0;u<4;++u){
      #pragma unroll
      for (int j=0;j<9;++j){ gi[u][j]=bi[j]; gh[u][j]=bh[j]; }
    }
    const float* cop[4];
    #pragma unroll
    for (int u=0;u<4;++u) cop[u] = &co[((size_t)btv[u]*N_ + cnv[u])*G_];
    for (int g=0; g<G_; ++g){
      const float* wr = &WihT[g*H3_];
      float wv[9];
      wv[0]=wr[h0]; wv[1]=wr[h0+H_]; wv[2]=wr[h0+2*H_];
      wv[3]=wr[h1]; wv[4]=wr[h1+H_]; wv[5]=wr[h1+2*H_];
      wv[6]=wr[h2c]; wv[7]=wr[h2c+H_]; wv[8]=wr[h2c+2*H_];
      #pragma unroll
      for (int u=0;u<4;++u){
        float cg = cop[u][g];
        #pragma unroll
        for (int j=0;j<9;++j) gi[u][j]=fmaf(cg, wv[j], gi[u][j]);
      }
    }
    for (int q=0;q<H_;++q){
      const float* wr=&WhhT[q*H3_];
      float wv[9];
      wv[0]=wr[h0]; wv[1]=wr[h0+H_]; wv[2]=wr[h0+2*H_];
      wv[3]=wr[h1]; wv[4]=wr[h1+H_]; wv[5]=wr[h1+2*H_];
      wv[6]=wr[h2c]; wv[7]=wr[h2c+H_]; wv[8]=wr[h2c+2*H_];
      #pragma unroll
      for (int u=0;u<4;++u){
        float hv = hp[u][q];
        #pragma unroll
        for (int j=0;j<9;++j) gh[u][j]=fmaf(hv, wv[j], gh[u][j]);
      }
    }
    #pragma unroll
    for (int u=0;u<4;++u){
      if (as[u]){
        float hv0 = hp[u][h0];
        float hv1 = hp[u][h1];
        float hv2 = has2 ? hp[u][h2] : 0.f;
        float r0=sigmf(gi[u][0]+gh[u][0]), z0=sigmf(gi[u][1]+gh[u][1]);
        float cd0=tanhf(gi[u][2]+r0*gh[u][2]);
        float o0=(1.f-z0)*cd0 + z0*hv0;
        float r1=sigmf(gi[u][3]+gh[u][3]), z1=sigmf(gi[u][4]+gh[u][4]);
        float cd1=tanhf(gi[u][5]+r1*gh[u][5]);
        float o1=(1.f-z1)*cd1 + z1*hv1;
        float o2=0.f;
        if (has2){
          float r2=sigmf(gi[u][6]+gh[u][6]), z2=sigmf(gi[u][7]+gh[u][7]);
          float cd2=tanhf(gi[u][8]+r2*gh[u][8]);
          o2=(1.f-z2)*cd2 + z2*hv2;
        }
        float* hd = &hst[w][u][0];
        hd[h0]=o0; hd[h1]=o1; if (has2) hd[h2]=o2;
        int pos = pos1[(size_t)btv[u]*N_ + cnv[u]];
        if (pos >= 0 && pos < CAP1){
          float* gd = &gout[((size_t)btv[u]*CAP1 + pos)*H_];
          gd[h0]=o0; gd[h1]=o1; if (has2) gd[h2]=o2;
        }
      }
    }
    asm volatile("s_waitcnt lgkmcnt(0)" ::: "memory");  // h stores visible before next s reads
  }
}

// ---------------- per-(b,t) max over m1 rows -> om1f ----------------
__global__ __launch_bounds__(256) void k_om1(
    const float* __restrict__ gout, const int* __restrict__ cnt1, float* __restrict__ om1f)
{
  int bt = blockIdx.x; int tid = threadIdx.x;
  int c1 = cnt1[bt]; if (c1 > CAP1) c1 = CAP1;
  if (tid < H_){
    float mx = -1e30f;
    for (int r=0;r<c1;++r) mx = fmaxf(mx, gout[((size_t)bt*CAP1+r)*H_+tid]);
    om1f[(size_t)bt*H_+tid] = (c1>0) ? mx : 0.f;
  }
}

// ---------------- final: outs assembly, pooling, output ----------------
__global__ __launch_bounds__(256) void k_final(
    const float* __restrict__ om1f, const float* __restrict__ om23f,
    const float* __restrict__ Wp, const float* __restrict__ bp,
    const float* __restrict__ ctx, const float* __restrict__ Wc, const float* __restrict__ bc,
    const int* __restrict__ lens, float* __restrict__ out)
{
  int b = blockIdx.x; int tid = threadIdx.x;
  __shared__ float sOut[T_][H_];
  __shared__ float sTP[T_][P_];
  __shared__ float sVu[T_], sSc[T_], sPool[H_];
  __shared__ float sRed[256];
  for (int i=tid; i<T_*H_; i+=256){
    int t=i/H_, h=i-t*H_;
    float o1 = om1f[((size_t)b*T_+t)*H_+h];
    float o2 = (t>0)? om23f[((size_t)b*T_+t)*H_+h] : 0.f;
    sOut[t][h]=o1+o2;
  }
  __syncthreads();
  for (int pr = tid; pr < T_*P_; pr += 256){
    int t = pr / P_, p = pr - t*P_;
    float acc = bp[p];
    for (int h=0;h<H_;++h) acc = fmaf(sOut[t][h], Wp[h*P_+p], acc);
    sTP[t][p] = acc * ctx[p];
  }
  __syncthreads();
  if (tid < T_){
    float v=0.f;
    for (int p=0;p<P_;++p) v += sTP[tid][p];
    sVu[tid]=v;
  }
  __syncthreads();
  if (tid==0){
    int L = lens[b]; if (L<1) L=1; if (L>T_) L=T_;
    float mx=-1e30f;
    for (int t=0;t<L;++t) mx = fmaxf(mx, sVu[t]);
    float s=0.f;
    for (int t=0;t<L;++t){ float e=__expf(sVu[t]-mx); sSc[t]=e; s+=e; }
    float inv=1.f/s;
    for (int t=0;t<T_;++t) sSc[t] = (t<L)? sSc[t]*inv : 0.f;
  }
  __syncthreads();
  if (tid < H_){
    float acc=0.f;
    for (int t=0;t<T_;++t) acc = fmaf(sOut[t][tid], sSc[t], acc);
    sPool[tid]=acc;
  }
  __syncthreads();
  float v = (tid<H_)? sPool[tid]*Wc[tid] : 0.f;
  sRed[tid]=v; __syncthreads();
  for (int s=128;s>0;s>>=1){ if (tid<s) sRed[tid]+=sRed[tid+s]; __syncthreads(); }
  if (tid==0) out[b] = sRed[0] + bc[0];
}

extern "C" void kernel_launch(void* const* d_in, const int* in_sizes, int n_in,
                              void* d_out, int out_size, void* d_ws, size_t ws_size,
                              hipStream_t stream)
{
  const float* code_x=(const float*)d_in[0];
  const int*   divided=(const int*)d_in[1];
  const float* neighbors=(const float*)d_in[2];
  const int*   lens=(const int*)d_in[3];
  const float* prior=(const float*)d_in[4];
  const float* adj=(const float*)d_in[5];
  const float* c_emb=(const float*)d_in[6];
  const float* n_emb=(const float*)d_in[7];
  const float* u_emb=(const float*)d_in[8];
  const float* Wg=(const float*)d_in[9];
  const float* bg=(const float*)d_in[10];
  const float* W_ih=(const float*)d_in[11];
  const float* b_ih=(const float*)d_in[12];
  const float* W_hh=(const float*)d_in[13];
  const float* b_hh=(const float*)d_in[14];
  const float* Wq=(const float*)d_in[15];
  const float* bq=(const float*)d_in[16];
  const float* Wk=(const float*)d_in[17];
  const float* bk=(const float*)d_in[18];
  const float* Wv=(const float*)d_in[19];
  const float* bv=(const float*)d_in[20];
  const float* Wp=(const float*)d_in[21];
  const float* bp=(const float*)d_in[22];
  const float* ctx=(const float*)d_in[23];
  const float* Wc=(const float*)d_in[24];
  const float* bc=(const float*)d_in[25];
  float* out=(float*)d_out;
  (void)in_sizes; (void)n_in; (void)out_size; (void)ws_size; (void)bk;

  char* p=(char*)d_ws;
  size_t off=0;
  auto carve=[&](size_t bytes)->char*{ char* r=p+off; off=(off+bytes+255)&~(size_t)255; return r; };
  int*   rowptr=(int*)carve((N_+1)*4);
  int*   rcnt  =(int*)carve(N_*4);
  int*   ccol  =(int*)carve((size_t)NNZ_CAP*4);
  float* cval  =(float*)carve((size_t)NNZ_CAP*4);
  int*   cnt23 =(int*)carve(B_*T_*4);
  int*   cnt1  =(int*)carve(B_*T_*4);
  int*   lst23 =(int*)carve((size_t)B_*T_*N_*4);
  int*   pos1  =(int*)carve((size_t)B_*T_*N_*4);
  float* co    =(float*)carve((size_t)B_*T_*N_*G_*4);
  float* no_   =(float*)carve((size_t)B_*T_*N_*G_*4);
  float* WihT  =(float*)carve((size_t)G_*H3_*4);
  float* WhhT  =(float*)carve((size_t)H_*H3_*4);
  float* Md    =(float*)carve(1056*4);
  float* hsel  =(float*)carve((size_t)B_*T_*CAP1*H_*4);
  float* gout  =(float*)carve((size_t)B_*T_*CAP1*H_*4);
  unsigned* chainsN=(unsigned*)carve((size_t)CHCAP*4);
  unsigned* chainsH=(unsigned*)carve((size_t)CHCAP*4);
  unsigned* chainsL=(unsigned*)carve((size_t)CHCAPL*4);
  int*   nchN  =(int*)carve(256);
  int*   nchH  =(int*)carve(256);
  int*   nchL  =(int*)carve(256);
  float* om1f  =(float*)carve((size_t)B_*T_*H_*4);
  float* om23f =(float*)carve((size_t)B_*T_*H_*4);

  k_csr_cnt<<<N_,256,0,stream>>>(adj, rcnt);
  k_csr_scan<<<1,64,0,stream>>>(rcnt, rowptr);
  k_csr_fill<<<N_,64,0,stream>>>(adj, prior, rowptr, ccol, cval);
  k_masks<<<B_*T_,64,0,stream>>>(divided, lst23, pos1, cnt23, cnt1);
  k_wt<<<325,256,0,stream>>>(W_ih, W_hh, Wq, bq, Wk, WihT, WhhT, Md);
  k_init<<<(B_*T_*H_+255)/256,256,0,stream>>>(om23f, nchN, nchH, nchL);
  k_chains<<<(B_*N_+255)/256,256,0,stream>>>(divided, chainsN, nchN, chainsH, nchH, chainsL, nchL);
  k_cono<<<B_*T_*N_/4,256,0,stream>>>(code_x, neighbors, divided, rowptr, ccol, cval,
                                      c_emb, n_emb, Wg, bg, co, no_);
  k_attn<<<dim3(B_, T_-1),384,0,stream>>>(co, no_, u_emb, divided,
                                      lst23, cnt23, pos1, Md, Wv, bv,
                                      hsel, om23f);
  k_gruheadN<<<CHCAP/16,256,0,stream>>>(co, pos1, chainsN, nchN,
                                      WihT, b_ih, b_hh, gout);
  k_gruheadH<<<CHCAP/16,256,0,stream>>>(co, hsel, pos1, chainsH, nchH,
                                      WihT, b_ih, WhhT, b_hh, gout);
  k_grutail<<<CHCAPL/16,256,0,stream>>>(co, pos1, chainsL, nchL,
                                      WihT, b_ih, WhhT, b_hh, gout);
  k_om1<<<B_*T_,256,0,stream>>>(gout, cnt1, om1f);
  k_final<<<B_,256,0,stream>>>(om1f, om23f, Wp,bp,ctx,Wc,bc, lens, out);
}

// Round 10
// 479.044 us; speedup vs baseline: 2.5040x; 1.0974x over previous
//
#include <hip/hip_runtime.h>

#define B_ 16
#define T_ 16
#define N_ 1024
#define C_ 48
#define G_ 32
#define H_ 150
#define A_ 32
#define P_ 32
#define H3_ 450
#define NNZ_CAP 262144
#define CAP1 256
#define CAP23 384
#define CHCAP 40960
#define CHCAPL 16384
#define SCALE_ 0.17677669529663687f

__device__ __forceinline__ unsigned fenc(float f){
  unsigned u = __float_as_uint(f);
  return (u & 0x80000000u) ? ~u : (u | 0x80000000u);
}
__device__ __forceinline__ float fdec(unsigned e){
  unsigned u = (e & 0x80000000u) ? (e & 0x7fffffffu) : ~e;
  return __uint_as_float(u);
}
__device__ __forceinline__ float sigmf(float x){ return 1.f/(1.f+__expf(-x)); }
__device__ __forceinline__ float wmaxf(float v){
  #pragma unroll
  for (int d=32; d>0; d>>=1) v = fmaxf(v, __shfl_xor(v,d));
  return v;
}

#define FMA16(W, PTR, ACC) do { \
    const float4* _c4 = (const float4*)(PTR); \
    float4 _c0=_c4[0], _c1=_c4[1], _c2=_c4[2], _c3=_c4[3]; \
    ACC[0]=fmaf((W),_c0.x,ACC[0]); ACC[1]=fmaf((W),_c0.y,ACC[1]); \
    ACC[2]=fmaf((W),_c0.z,ACC[2]); ACC[3]=fmaf((W),_c0.w,ACC[3]); \
    ACC[4]=fmaf((W),_c1.x,ACC[4]); ACC[5]=fmaf((W),_c1.y,ACC[5]); \
    ACC[6]=fmaf((W),_c1.z,ACC[6]); ACC[7]=fmaf((W),_c1.w,ACC[7]); \
    ACC[8]=fmaf((W),_c2.x,ACC[8]); ACC[9]=fmaf((W),_c2.y,ACC[9]); \
    ACC[10]=fmaf((W),_c2.z,ACC[10]); ACC[11]=fmaf((W),_c2.w,ACC[11]); \
    ACC[12]=fmaf((W),_c3.x,ACC[12]); ACC[13]=fmaf((W),_c3.y,ACC[13]); \
    ACC[14]=fmaf((W),_c3.z,ACC[14]); ACC[15]=fmaf((W),_c3.w,ACC[15]); \
  } while(0)

// ---------------- CSR build for adj (5% dense), prior folded into cval ----------------
__global__ void k_csr_cnt(const float* __restrict__ adj, int* __restrict__ rcnt){
  int m = blockIdx.x; int tid = threadIdx.x;
  int c = 0;
  for (int n = tid; n < N_; n += 256) c += (adj[(size_t)m*N_+n] != 0.f) ? 1 : 0;
  __shared__ int sr[256];
  sr[tid]=c; __syncthreads();
  for (int s=128; s>0; s>>=1){ if (tid<s) sr[tid]+=sr[tid+s]; __syncthreads(); }
  if (tid==0) rcnt[m]=sr[0];
}
__global__ void k_csr_scan(const int* __restrict__ rcnt, int* __restrict__ rowptr){
  int lane = threadIdx.x; // 64 threads
  int s = 0;
  for (int r=0;r<16;++r) s += rcnt[lane*16+r];
  int incl = s;
  for (int d=1; d<64; d<<=1){ int y = __shfl_up(incl, d); if (lane>=d) incl += y; }
  int run = incl - s;
  for (int r=0;r<16;++r){ rowptr[lane*16+r] = run; run += rcnt[lane*16+r]; }
  if (lane==63) rowptr[N_] = incl;
}
__global__ void k_csr_fill(const float* __restrict__ adj, const float* __restrict__ prior,
                           const int* __restrict__ rowptr,
                           int* __restrict__ ccol, float* __restrict__ cval){
  int m = blockIdx.x; int lane = threadIdx.x; // 64
  int base = rowptr[m];
  float pm = prior[m];
  for (int it=0; it<N_/64; ++it){
    int n = it*64+lane;
    float a = adj[(size_t)m*N_+n];
    bool pnz = (a != 0.f);
    unsigned long long mk = __ballot(pnz);
    if (pnz){
      int idx = base + __popcll(mk & ((1ULL<<lane)-1ULL));
      if (idx < NNZ_CAP){ ccol[idx]=n; cval[idx]=a*pm; }
    }
    base += __popcll(mk);
  }
}

// ---------------- mask compaction: lst23 + pos1 + counts ----------------
__global__ void k_masks(const int* __restrict__ divided, int* __restrict__ lst23,
                        int* __restrict__ pos1,
                        int* __restrict__ cnt23, int* __restrict__ cnt1){
  int bt = blockIdx.x; int lane = threadIdx.x; // 64
  int base23=0, base1=0;
  for (int it=0; it<N_/64; ++it){
    int n = it*64+lane;
    const int* dv = &divided[((size_t)bt*N_+n)*3];
    int d0=dv[0], d1=dv[1], d2=dv[2];
    bool p23 = (d1>0)||(d2>0); bool p1 = d0>0;
    unsigned long long mk23 = __ballot(p23);
    unsigned long long mk1  = __ballot(p1);
    unsigned long long ltm = (1ULL<<lane)-1ULL;
    if (p23){ int idx = base23 + __popcll(mk23 & ltm); lst23[(size_t)bt*N_+idx]=n; }
    if (p1){ int idx = base1 + __popcll(mk1 & ltm); pos1[(size_t)bt*N_+n]=idx; }
    base23 += __popcll(mk23); base1 += __popcll(mk1);
  }
  if (lane==0){ cnt23[bt]=base23; cnt1[bt]=base1; }
}

// ---------------- chain extraction: split heads into NoH / H lists; tails (len>=2) ----------------
__global__ void k_chains(const int* __restrict__ divided,
                         unsigned* __restrict__ chN, int* __restrict__ nchN,
                         unsigned* __restrict__ chH, int* __restrict__ nchH,
                         unsigned* __restrict__ chL, int* __restrict__ nchL){
  int idx = blockIdx.x*256 + threadIdx.x;   // over B*N
  if (idx >= B_*N_) return;
  int b = idx >> 10, n = idx & (N_-1);
  unsigned m1m = 0;
  for (int t=0;t<T_;++t){
    int d0 = divided[(((size_t)(b*T_+t))*N_ + n)*3];
    if (d0>0) m1m |= (1u<<t);
  }
  unsigned heads = m1m & ~(m1m<<1);
  while (heads){
    int t0 = __builtin_ctz(heads); heads &= (heads-1u);
    unsigned run = m1m >> t0;
    int len = __builtin_ctz(~run);   // trailing ones = chain length
    unsigned enc = ((unsigned)b<<18)|((unsigned)n<<8)|((unsigned)t0<<4)|(unsigned)(len-1);
    int f = 0;
    if (t0 >= 2){
      size_t pidx = ((size_t)(b*T_+t0-1)*N_ + n)*3;
      if ((divided[pidx+1] | divided[pidx+2]) > 0) f = 1;
    }
    if (f){ int i2 = atomicAdd(nchH,1); if (i2 < CHCAP) chH[i2]=enc; }
    else  { int i2 = atomicAdd(nchN,1); if (i2 < CHCAP) chN[i2]=enc; }
    if (len >= 2){
      int i2 = atomicAdd(nchL, 1);
      if (i2 < CHCAPL) chL[i2] = enc;
    }
  }
}

// ---------------- weight transposes + fused q-projection matrix M = Wq Wk^T, d = Wk bq; WvT ----------------
__global__ void k_wt(const float* __restrict__ W_ih, const float* __restrict__ W_hh,
                     const float* __restrict__ Wq, const float* __restrict__ bq,
                     const float* __restrict__ Wk, const float* __restrict__ Wv,
                     float* __restrict__ WihT, float* __restrict__ WhhT,
                     float* __restrict__ Md, float* __restrict__ WvT){
  int idx = blockIdx.x*256+threadIdx.x;
  if (idx < G_*H3_){ int g=idx/H3_, k=idx-g*H3_; WihT[g*H3_+k]=W_ih[(size_t)k*G_+g]; }
  int idx2 = idx - G_*H3_;
  if (idx2>=0 && idx2 < H_*H3_){ int h=idx2/H3_, k=idx2-h*H3_; WhhT[h*H3_+k]=W_hh[(size_t)k*H_+h]; }
  int e = idx - (G_*H3_ + H_*H3_);
  if (e>=0 && e<1024){
    int g=e>>5, gp=e&31;
    float acc=0.f;
    #pragma unroll
    for (int a=0;a<A_;++a) acc = fmaf(Wq[g*A_+a], Wk[gp*A_+a], acc);
    Md[e]=acc;
  }
  int e2 = e - 1024;
  if (e2>=0 && e2<32){
    float acc=0.f;
    #pragma unroll
    for (int a=0;a<A_;++a) acc = fmaf(Wk[e2*A_+a], bq[a], acc);
    Md[1024+e2]=acc;
  }
  int e3 = e - 1056;
  if (e3>=0 && e3 < H_*G_){
    int h = e3>>5, g = e3&31;
    WvT[e3] = Wv[(size_t)g*H_+h];
  }
}

__global__ void k_init(float* __restrict__ om23f, int* __restrict__ nchN,
                       int* __restrict__ nchH, int* __restrict__ nchL){
  int i = blockIdx.x*256+threadIdx.x;
  if (i<B_*T_*H_){ om23f[i]=0.f; }
  if (i==0){ *nchN = 0; *nchH = 0; *nchL = 0; }
}

// ---------------- fused agg -> co,no, demand-driven (only rows consumers read) ----------------
__global__ __launch_bounds__(256) void k_cono(
    const float* __restrict__ code_x, const float* __restrict__ neighbors,
    const int* __restrict__ divided,
    const int* __restrict__ rowptr, const int* __restrict__ ccol, const float* __restrict__ cval,
    const float* __restrict__ c_emb, const float* __restrict__ n_emb,
    const float* __restrict__ Wg, const float* __restrict__ bg,
    float* __restrict__ co, float* __restrict__ no_)
{
  __shared__ float sCo[4][C_], sNo[4][C_];
  int w = threadIdx.x >> 6, lane = threadIdx.x & 63;
  int gw = blockIdx.x*4 + w;            // row over B*T*N
  int bt = gw >> 10, m = gw & (N_-1);
  int t = bt & (T_-1);
  const int* dv = &divided[(size_t)gw*3];
  int d0=dv[0], d1=dv[1], d2=dv[2];
  bool needCo = (d0|d1|d2) > 0;                 // read by attn (m23) or GRU (m1)
  bool needNo = (t < T_-1) && (divided[((size_t)(gw+N_))*3+1] > 0); // read as q-source at t+1
  if (!needCo && !needNo) return;               // wave-uniform (wave == row)
  float cxm = code_x[gw], nbm = neighbors[gw];
  float acc = 0.f;
  bool needAcc = (needCo && cxm!=0.f) || (needNo && nbm!=0.f);
  if (needAcc){
    int s = rowptr[m], e = rowptr[m+1];
    if (s > NNZ_CAP) s = NNZ_CAP;
    if (e > NNZ_CAP) e = NNZ_CAP;
    int btN = bt << 10;
    for (int base = s; base < e; base += 64){
      int j = base + lane;
      int cc = 0; float wx = 0.f, wy = 0.f;
      if (j < e){
        cc = ccol[j];
        float cv = cval[j];
        float xs = code_x[btN+cc], ys = neighbors[btN+cc];
        wx = cv*xs; wy = cv*ys;
      }
      unsigned long long mk = __ballot(wx!=0.f || wy!=0.f);
      while (mk){
        int u0 = __builtin_ctzll(mk); mk &= (mk-1ULL);
        int u1 = -1;
        if (mk){ u1 = __builtin_ctzll(mk); mk &= (mk-1ULL); }
        int u1s = (u1>=0)? u1 : u0;
        int n0 = __shfl(cc,u0); float a0x=__shfl(wx,u0), a0y=__shfl(wy,u0);
        int n1 = __shfl(cc,u1s); float a1x=__shfl(wx,u1s), a1y=__shfl(wy,u1s);
        float ce0=0.f,ne0=0.f,ce1=0.f,ne1=0.f;
        if (lane < C_){
          ce0 = c_emb[(size_t)n0*C_+lane]; ne0 = n_emb[(size_t)n0*C_+lane];
          ce1 = c_emb[(size_t)n1*C_+lane]; ne1 = n_emb[(size_t)n1*C_+lane];
        }
        acc = fmaf(a0x, ce0, acc); acc = fmaf(a0y, ne0, acc);
        if (u1>=0){ acc = fmaf(a1x, ce1, acc); acc = fmaf(a1y, ne1, acc); }
      }
    }
  }
  if (lane < C_){
    sCo[w][lane] = cxm * (c_emb[(size_t)m*C_+lane] + acc);
    sNo[w][lane] = nbm * (n_emb[(size_t)m*C_+lane] + acc);
  }
  asm volatile("s_waitcnt lgkmcnt(0)" ::: "memory");   // wave-local LDS fence
  int g = lane & 31; bool isNo = lane >= 32;
  const float* src = isNo ? sNo[w] : sCo[w];
  float a2 = bg[g];
  #pragma unroll
  for (int c=0;c<C_;++c) a2 = fmaf(src[c], Wg[c*G_+g], a2);
  float r = a2 >= 0.f ? a2 : 0.01f*a2;
  if (isNo ? needNo : needCo){
    float* dst = isNo ? no_ : co;
    dst[(size_t)gw*G_ + g] = r;
  }
}

// ---------------- attention v3: 768 thr/block, column-split, in-place pbar combine ----------------
__global__ __launch_bounds__(768) void k_attn(
    const float* __restrict__ co, const float* __restrict__ no_,
    const float* __restrict__ u_emb, const int* __restrict__ divided,
    const int* __restrict__ lst23, const int* __restrict__ cnt23, const int* __restrict__ pos1,
    const float* __restrict__ Md, const float* __restrict__ WvT, const float* __restrict__ bv,
    float* __restrict__ hsel, float* __restrict__ om23f)
{
  int b = blockIdx.x; int t = blockIdx.y + 1; int bt = b*T_ + t;
  int cnt = cnt23[bt]; if (cnt > CAP23) cnt = CAP23;
  if (cnt == 0) return;   // om23f zeroed by k_init
  __shared__ int   sLst[CAP23];
  __shared__ __align__(16) float sCo[CAP23][G_];   // 48KB; later reused as combined pbar
  __shared__ float sL[CAP23];
  __shared__ unsigned sMax[H_];
  int tid = threadIdx.x;
  int grp = (tid >= 384) ? 1 : 0;
  int r   = tid - 384*grp;
  unsigned sent = fenc(-1e30f);
  for (int i=tid; i<cnt; i+=768) sLst[i] = lst23[(size_t)bt*N_+i];
  for (int i=tid; i<H_; i+=768) sMax[i] = sent;
  __syncthreads();
  for (int i=tid; i<cnt*8; i+=768){
    int rrow = i>>3, seg = i&7;
    float4 v = *(const float4*)&co[((((size_t)bt<<10) + sLst[rrow])<<5) + seg*4];
    *(float4*)&sCo[rrow][seg*4] = v;
  }
  bool act = (r < cnt);
  int n = 0;
  float qpp[G_];
  if (act){
    n = sLst[r];
    int d1 = divided[((size_t)bt*N_+n)*3+1];
    const float* qsrc = (d1>0) ? &no_[((((size_t)(bt-1))<<10)+n)<<5] : &u_emb[(size_t)n*G_];
    float4 qv[8];
    #pragma unroll
    for (int j=0;j<8;++j) qv[j] = ((const float4*)qsrc)[j];
    #pragma unroll
    for (int j=0;j<G_;++j) qpp[j] = Md[1024+j];
    #pragma unroll
    for (int g=0; g<G_; ++g){
      float qfg = (g&3)==0 ? qv[g>>2].x : (g&3)==1 ? qv[g>>2].y : (g&3)==2 ? qv[g>>2].z : qv[g>>2].w;
      const float4* mr = (const float4*)&Md[g*G_];   // wave-broadcast, L2-hot
      #pragma unroll
      for (int j=0;j<8;++j){
        float4 mj = mr[j];
        qpp[4*j+0] = fmaf(qfg, mj.x, qpp[4*j+0]);
        qpp[4*j+1] = fmaf(qfg, mj.y, qpp[4*j+1]);
        qpp[4*j+2] = fmaf(qfg, mj.z, qpp[4*j+2]);
        qpp[4*j+3] = fmaf(qfg, mj.w, qpp[4*j+3]);
      }
    }
  } else {
    #pragma unroll
    for (int j=0;j<G_;++j) qpp[j]=0.f;
  }
  __syncthreads();   // sCo staged
  // column-split fused score+softmax+PV pass
  int half = (cnt+1)>>1;
  int c0 = grp ? half : 0;
  int c1 = grp ? cnt  : half;
  float pbar[G_]; float l = 0.f;
  #pragma unroll
  for (int j=0;j<G_;++j) pbar[j]=0.f;
  if (act){
    #pragma unroll 2
    for (int c=c0;c<c1;++c){
      const float4* col = (const float4*)&sCo[c][0];
      float4 xv[8];
      #pragma unroll
      for (int j=0;j<8;++j) xv[j]=col[j];
      float d0=0.f,d1v=0.f,d2v=0.f,d3=0.f;
      #pragma unroll
      for (int j=0;j<8;j+=4){
        d0 = fmaf(qpp[4*j+0], xv[j].x, d0); d1v = fmaf(qpp[4*j+1], xv[j].y, d1v);
        d2v = fmaf(qpp[4*j+2], xv[j].z, d2v); d3 = fmaf(qpp[4*j+3], xv[j].w, d3);
        d0 = fmaf(qpp[4*j+4], xv[j+1].x, d0); d1v = fmaf(qpp[4*j+5], xv[j+1].y, d1v);
        d2v = fmaf(qpp[4*j+6], xv[j+1].z, d2v); d3 = fmaf(qpp[4*j+7], xv[j+1].w, d3);
        d0 = fmaf(qpp[4*j+8], xv[j+2].x, d0); d1v = fmaf(qpp[4*j+9], xv[j+2].y, d1v);
        d2v = fmaf(qpp[4*j+10], xv[j+2].z, d2v); d3 = fmaf(qpp[4*j+11], xv[j+2].w, d3);
        d0 = fmaf(qpp[4*j+12], xv[j+3].x, d0); d1v = fmaf(qpp[4*j+13], xv[j+3].y, d1v);
        d2v = fmaf(qpp[4*j+14], xv[j+3].z, d2v); d3 = fmaf(qpp[4*j+15], xv[j+3].w, d3);
      }
      float dot = (d0+d1v)+(d2v+d3);
      float pv = __expf(dot*SCALE_);
      l += pv;
      #pragma unroll
      for (int j=0;j<8;++j){
        pbar[4*j+0] = fmaf(pv, xv[j].x, pbar[4*j+0]);
        pbar[4*j+1] = fmaf(pv, xv[j].y, pbar[4*j+1]);
        pbar[4*j+2] = fmaf(pv, xv[j].z, pbar[4*j+2]);
        pbar[4*j+3] = fmaf(pv, xv[j].w, pbar[4*j+3]);
      }
    }
  }
  __syncthreads();   // everyone done READING sCo -> safe to overwrite
  if (act && grp==0){
    #pragma unroll
    for (int j=0;j<G_;++j) sCo[r][j] = pbar[j];
    sL[r] = l;
  }
  __syncthreads();
  if (act && grp==1){
    #pragma unroll
    for (int j=0;j<G_;++j) sCo[r][j] += pbar[j];
    sL[r] += l;
  }
  __syncthreads();
  // normalized pbar
  float pb[G_];
  if (act){
    float inv = 1.f / sL[r];
    const float4* pr = (const float4*)&sCo[r][0];
    #pragma unroll
    for (int j=0;j<8;++j){
      float4 pv4 = pr[j];
      pb[4*j+0]=pv4.x*inv; pb[4*j+1]=pv4.y*inv; pb[4*j+2]=pv4.z*inv; pb[4*j+3]=pv4.w*inv;
    }
  } else {
    #pragma unroll
    for (int j=0;j<G_;++j) pb[j]=0.f;
  }
  bool wsel=false; float* hd=nullptr;
  if (act && t+1 < T_){
    size_t nidx = ((size_t)b*T_+(t+1))*N_ + n;
    if (divided[nidx*3+0] > 0){
      int pos = pos1[nidx];
      if (pos >= 0 && pos < CAP1){ wsel=true; hd=&hsel[(((size_t)b*T_+t)*CAP1 + pos)*H_]; }
    }
  }
  int lane = tid & 63;
  int hA = grp*75, hB = hA + 75;   // H_=150 split across groups
  for (int h=hA; h<hB; ++h){
    float acc = bv[h];
    const float4* wr = (const float4*)&WvT[h*G_];   // wave-broadcast, L2-hot
    #pragma unroll
    for (int j=0;j<8;++j){
      float4 wj = wr[j];
      acc = fmaf(pb[4*j+0], wj.x, acc);
      acc = fmaf(pb[4*j+1], wj.y, acc);
      acc = fmaf(pb[4*j+2], wj.z, acc);
      acc = fmaf(pb[4*j+3], wj.w, acc);
    }
    float o = act ? tanhf(acc) : -1e30f;
    float om = wmaxf(o);
    if (lane==0) atomicMax(&sMax[h], fenc(om));
    if (wsel) hd[h] = o;
  }
  __syncthreads();
  for (int i=tid; i<H_; i+=768) om23f[(size_t)bt*H_+i] = fdec(sMax[i]);
}

// ---------------- GRU heads WITHOUT h_prev: ih-GEMM only, ~31KB LDS ----------------
__global__ __launch_bounds__(256) void k_gruheadN(
    const float* __restrict__ co, const int* __restrict__ pos1,
    const unsigned* __restrict__ chN, const int* __restrict__ nchN,
    const float* __restrict__ WihT, const float* __restrict__ b_ih,
    const float* __restrict__ b_hh, float* __restrict__ gout)
{
  __shared__ __align__(16) float sCoT[G_][16];   // 2KB (transposed)
  __shared__ float sG[16][452];                  // 28.9KB
  __shared__ int sBt[16], sN[16], sPos[16];
  int tid = threadIdx.x;
  int NC = *nchN; if (NC > CHCAP) NC = CHCAP;
  int base = blockIdx.x * 16;
  if (base >= NC) return;
  int num = min(16, NC - base);
  if (tid < 16){
    if (tid < num){
      unsigned cl = chN[base+tid];
      int b = cl>>18, n = (cl>>8)&1023, t0 = (cl>>4)&15;
      int bt = b*T_ + t0;
      sBt[tid]=bt; sN[tid]=n; sPos[tid]=pos1[(size_t)bt*N_+n];
    } else { sBt[tid]=0; sN[tid]=0; sPos[tid]=-1; }
  }
  __syncthreads();
  for (int i=tid; i<G_*16; i+=256){
    int g = i>>4, ii = i&15;
    sCoT[g][ii] = (ii<num) ? co[((size_t)sBt[ii]*N_+sN[ii])*G_+g] : 0.f;
  }
  __syncthreads();
  for (int pass=0; pass<2; ++pass){
    int k = pass*256 + tid;
    if (k < H3_){
      float acc[16];
      #pragma unroll
      for (int u=0;u<16;++u) acc[u]=0.f;
      for (int g=0; g<G_; ++g){
        float wih = WihT[g*H3_ + k];
        FMA16(wih, &sCoT[g][0], acc);
      }
      #pragma unroll
      for (int u=0;u<16;++u) sG[u][k] = acc[u];
    }
  }
  __syncthreads();
  for (int i=tid; i<num*152; i+=256){
    int s = i/152, h = i - s*152;
    if (h < H_){
      int pos = sPos[s];
      if (pos >= 0 && pos < CAP1){
        float r = sigmf(sG[s][h]       + b_ih[h]       + b_hh[h]);
        float z = sigmf(sG[s][h+H_]    + b_ih[h+H_]    + b_hh[h+H_]);
        float cand = tanhf(sG[s][h+2*H_] + b_ih[h+2*H_] + r*b_hh[h+2*H_]);
        gout[((size_t)sBt[s]*CAP1 + pos)*H_ + h] = (1.f-z)*cand;
      }
    }
  }
}

// ---------------- GRU heads WITH h_prev: ih + hh GEMMs, all 16 slots active ----------------
__global__ __launch_bounds__(256) void k_gruheadH(
    const float* __restrict__ co, const float* __restrict__ hsel,
    const int* __restrict__ pos1,
    const unsigned* __restrict__ chH, const int* __restrict__ nchH,
    const float* __restrict__ WihT, const float* __restrict__ b_ih,
    const float* __restrict__ WhhT, const float* __restrict__ b_hh,
    float* __restrict__ gout)
{
  __shared__ __align__(16) float sCoT[G_][16];   // 2KB
  __shared__ __align__(16) float sHT[152][16];   // 9.73KB (transposed h_prev)
  __shared__ float sG[16][452];                  // 28.9KB (r,z: ih+hh; n: ih)
  __shared__ float sGhn[16][152];                // 9.73KB (hh n-gate)
  __shared__ int sBt[16], sN[16], sPos[16], sHo[16];
  int tid = threadIdx.x;
  int NC = *nchH; if (NC > CHCAP) NC = CHCAP;
  int base = blockIdx.x * 16;
  if (base >= NC) return;
  int num = min(16, NC - base);
  if (tid < 16){
    if (tid < num){
      unsigned cl = chH[base+tid];
      int b = cl>>18, n = (cl>>8)&1023, t0 = (cl>>4)&15;
      int bt = b*T_ + t0;
      int pos = pos1[(size_t)bt*N_+n];
      sBt[tid]=bt; sN[tid]=n; sPos[tid]=pos;
      sHo[tid] = (b*T_ + (t0-1))*CAP1 + ((pos>=0 && pos<CAP1) ? pos : 0);
    } else { sBt[tid]=0; sN[tid]=0; sPos[tid]=-1; sHo[tid]=0; }
  }
  __syncthreads();
  for (int i=tid; i<G_*16; i+=256){
    int g = i>>4, ii = i&15;
    sCoT[g][ii] = (ii<num) ? co[((size_t)sBt[ii]*N_+sN[ii])*G_+g] : 0.f;
  }
  for (int i=tid; i<152*16; i+=256){
    int q = i>>4, ii = i&15;
    float v = 0.f;
    if (ii < num && q < H_) v = hsel[(size_t)sHo[ii]*H_ + q];
    sHT[q][ii] = v;
  }
  __syncthreads();
  // Phase A: ih-GEMM
  for (int pass=0; pass<2; ++pass){
    int k = pass*256 + tid;
    if (k < H3_){
      float acc[16];
      #pragma unroll
      for (int u=0;u<16;++u) acc[u]=0.f;
      for (int g=0; g<G_; ++g){
        float wih = WihT[g*H3_ + k];
        FMA16(wih, &sCoT[g][0], acc);
      }
      #pragma unroll
      for (int u=0;u<16;++u) sG[u][k] = acc[u];
    }
  }
  // Phase B: hh-GEMM, WhhT loaded once per (q,k), all 16 slots
  for (int pass=0; pass<2; ++pass){
    int k = pass*256 + tid;
    if (k < H3_){
      float acc[16];
      #pragma unroll
      for (int u=0;u<16;++u) acc[u]=0.f;
      for (int q=0; q<H_; ++q){
        float whh = WhhT[q*H3_ + k];
        FMA16(whh, &sHT[q][0], acc);
      }
      if (k < 2*H_){
        #pragma unroll
        for (int u=0;u<16;++u) sG[u][k] += acc[u];
      } else {
        #pragma unroll
        for (int u=0;u<16;++u) sGhn[u][k-2*H_] = acc[u];
      }
    }
  }
  __syncthreads();
  for (int i=tid; i<num*152; i+=256){
    int s = i/152, h = i - s*152;
    if (h < H_){
      int pos = sPos[s];
      if (pos >= 0 && pos < CAP1){
        float hv = sHT[h][s];
        float r = sigmf(sG[s][h]       + b_ih[h]       + b_hh[h]);
        float z = sigmf(sG[s][h+H_]    + b_ih[h+H_]    + b_hh[h+H_]);
        float cand = tanhf(sG[s][h+2*H_] + b_ih[h+2*H_] + r*(sGhn[s][h] + b_hh[h+2*H_]));
        float o = (1.f-z)*cand + z*hv;
        gout[((size_t)sBt[s]*CAP1 + pos)*H_ + h] = o;
      }
    }
  }
}

// ---------------- GRU chain TAILS (len>=2): serial walk s=1.., 4 chains/wave ----------------
__global__ __launch_bounds__(256) void k_grutail(
    const float* __restrict__ co, const int* __restrict__ pos1,
    const unsigned* __restrict__ chainsL, const int* __restrict__ nchL,
    const float* __restrict__ WihT, const float* __restrict__ b_ih,
    const float* __restrict__ WhhT, const float* __restrict__ b_hh,
    float* __restrict__ gout)
{
  __shared__ float hst[4][4][H_];   // 9.6KB
  int w = threadIdx.x >> 6, lane = threadIdx.x & 63;
  int NC = *nchL; if (NC > CHCAPL) NC = CHCAPL;
  int cbase = (blockIdx.x*4 + w)*4;
  if (cbase >= NC) return;

  int cbv[4], cnv[4], t0v[4], lenv[4];
  #pragma unroll
  for (int u=0;u<4;++u){
    int cid = cbase+u; bool ca = cid < NC;
    unsigned cl = chainsL[ca ? cid : (NC-1)];
    cbv[u]=cl>>18; cnv[u]=(cl>>8)&1023; t0v[u]=(cl>>4)&15;
    lenv[u]= ca ? (int)((cl&15)+1) : 1;   // inactive -> len 1 -> no s>=1 steps
  }
  int maxlen = lenv[0];
  #pragma unroll
  for (int u=1;u<4;++u) maxlen = max(maxlen, lenv[u]);

  int h0=lane,h1=lane+64,h2=lane+128; bool has2=(h2<H_); int h2c=has2?h2:0;
  float bi[9], bh[9];
  bi[0]=b_ih[h0]; bi[1]=b_ih[h0+H_]; bi[2]=b_ih[h0+2*H_];
  bi[3]=b_ih[h1]; bi[4]=b_ih[h1+H_]; bi[5]=b_ih[h1+2*H_];
  bi[6]=b_ih[h2c]; bi[7]=b_ih[h2c+H_]; bi[8]=b_ih[h2c+2*H_];
  bh[0]=b_hh[h0]; bh[1]=b_hh[h0+H_]; bh[2]=b_hh[h0+2*H_];
  bh[3]=b_hh[h1]; bh[4]=b_hh[h1+H_]; bh[5]=b_hh[h1+2*H_];
  bh[6]=b_hh[h2c]; bh[7]=b_hh[h2c+H_]; bh[8]=b_hh[h2c+2*H_];

  for (int s=1; s<maxlen; ++s){
    bool as[4]; int btv[4];
    const float* hp[4];
    #pragma unroll
    for (int u=0;u<4;++u){
      as[u] = s < lenv[u];
      int t = t0v[u] + (as[u] ? s : 0);
      btv[u] = cbv[u]*T_ + t;
      if (s == 1 && as[u]){
        int btp = btv[u] - 1;
        int posp = pos1[(size_t)btp*N_ + cnv[u]];
        if (posp < 0 || posp >= CAP1) posp = 0;
        hp[u] = &gout[((size_t)btp*CAP1 + posp)*H_];
      } else {
        hp[u] = &hst[w][u][0];
      }
    }
    float gi[4][9], gh[4][9];
    #pragma unroll
    for (int u=0;u<4;++u){
      #pragma unroll
      for (int j=0;j<9;++j){ gi[u][j]=bi[j]; gh[u][j]=bh[j]; }
    }
    const float* cop[4];
    #pragma unroll
    for (int u=0;u<4;++u) cop[u] = &co[((size_t)btv[u]*N_ + cnv[u])*G_];
    for (int g=0; g<G_; ++g){
      const float* wr = &WihT[g*H3_];
      float wv[9];
      wv[0]=wr[h0]; wv[1]=wr[h0+H_]; wv[2]=wr[h0+2*H_];
      wv[3]=wr[h1]; wv[4]=wr[h1+H_]; wv[5]=wr[h1+2*H_];
      wv[6]=wr[h2c]; wv[7]=wr[h2c+H_]; wv[8]=wr[h2c+2*H_];
      #pragma unroll
      for (int u=0;u<4;++u){
        float cg = cop[u][g];
        #pragma unroll
        for (int j=0;j<9;++j) gi[u][j]=fmaf(cg, wv[j], gi[u][j]);
      }
    }
    for (int q=0;q<H_;++q){
      const float* wr=&WhhT[q*H3_];
      float wv[9];
      wv[0]=wr[h0]; wv[1]=wr[h0+H_]; wv[2]=wr[h0+2*H_];
      wv[3]=wr[h1]; wv[4]=wr[h1+H_]; wv[5]=wr[h1+2*H_];
      wv[6]=wr[h2c]; wv[7]=wr[h2c+H_]; wv[8]=wr[h2c+2*H_];
      #pragma unroll
      for (int u=0;u<4;++u){
        float hv = hp[u][q];
        #pragma unroll
        for (int j=0;j<9;++j) gh[u][j]=fmaf(hv, wv[j], gh[u][j]);
      }
    }
    #pragma unroll
    for (int u=0;u<4;++u){
      if (as[u]){
        float hv0 = hp[u][h0];
        float hv1 = hp[u][h1];
        float hv2 = has2 ? hp[u][h2] : 0.f;
        float r0=sigmf(gi[u][0]+gh[u][0]), z0=sigmf(gi[u][1]+gh[u][1]);
        float cd0=tanhf(gi[u][2]+r0*gh[u][2]);
        float o0=(1.f-z0)*cd0 + z0*hv0;
        float r1=sigmf(gi[u][3]+gh[u][3]), z1=sigmf(gi[u][4]+gh[u][4]);
        float cd1=tanhf(gi[u][5]+r1*gh[u][5]);
        float o1=(1.f-z1)*cd1 + z1*hv1;
        float o2=0.f;
        if (has2){
          float r2=sigmf(gi[u][6]+gh[u][6]), z2=sigmf(gi[u][7]+gh[u][7]);
          float cd2=tanhf(gi[u][8]+r2*gh[u][8]);
          o2=(1.f-z2)*cd2 + z2*hv2;
        }
        float* hd = &hst[w][u][0];
        hd[h0]=o0; hd[h1]=o1; if (has2) hd[h2]=o2;
        int pos = pos1[(size_t)btv[u]*N_ + cnv[u]];
        if (pos >= 0 && pos < CAP1){
          float* gd = &gout[((size_t)btv[u]*CAP1 + pos)*H_];
          gd[h0]=o0; gd[h1]=o1; if (has2) gd[h2]=o2;
        }
      }
    }
    asm volatile("s_waitcnt lgkmcnt(0)" ::: "memory");  // h stores visible before next s reads
  }
}

// ---------------- per-(b,t) max over m1 rows -> om1f ----------------
__global__ __launch_bounds__(256) void k_om1(
    const float* __restrict__ gout, const int* __restrict__ cnt1, float* __restrict__ om1f)
{
  int bt = blockIdx.x; int tid = threadIdx.x;
  int c1 = cnt1[bt]; if (c1 > CAP1) c1 = CAP1;
  if (tid < H_){
    float mx = -1e30f;
    for (int r=0;r<c1;++r) mx = fmaxf(mx, gout[((size_t)bt*CAP1+r)*H_+tid]);
    om1f[(size_t)bt*H_+tid] = (c1>0) ? mx : 0.f;
  }
}

// ---------------- final: outs assembly, pooling, output ----------------
__global__ __launch_bounds__(256) void k_final(
    const float* __restrict__ om1f, const float* __restrict__ om23f,
    const float* __restrict__ Wp, const float* __restrict__ bp,
    const float* __restrict__ ctx, const float* __restrict__ Wc, const float* __restrict__ bc,
    const int* __restrict__ lens, float* __restrict__ out)
{
  int b = blockIdx.x; int tid = threadIdx.x;
  __shared__ float sOut[T_][H_];
  __shared__ float sTP[T_][P_];
  __shared__ float sVu[T_], sSc[T_], sPool[H_];
  __shared__ float sRed[256];
  for (int i=tid; i<T_*H_; i+=256){
    int t=i/H_, h=i-t*H_;
    float o1 = om1f[((size_t)b*T_+t)*H_+h];
    float o2 = (t>0)? om23f[((size_t)b*T_+t)*H_+h] : 0.f;
    sOut[t][h]=o1+o2;
  }
  __syncthreads();
  for (int pr = tid; pr < T_*P_; pr += 256){
    int t = pr / P_, p = pr - t*P_;
    float acc = bp[p];
    for (int h=0;h<H_;++h) acc = fmaf(sOut[t][h], Wp[h*P_+p], acc);
    sTP[t][p] = acc * ctx[p];
  }
  __syncthreads();
  if (tid < T_){
    float v=0.f;
    for (int p=0;p<P_;++p) v += sTP[tid][p];
    sVu[tid]=v;
  }
  __syncthreads();
  if (tid==0){
    int L = lens[b]; if (L<1) L=1; if (L>T_) L=T_;
    float mx=-1e30f;
    for (int t=0;t<L;++t) mx = fmaxf(mx, sVu[t]);
    float s=0.f;
    for (int t=0;t<L;++t){ float e=__expf(sVu[t]-mx); sSc[t]=e; s+=e; }
    float inv=1.f/s;
    for (int t=0;t<T_;++t) sSc[t] = (t<L)? sSc[t]*inv : 0.f;
  }
  __syncthreads();
  if (tid < H_){
    float acc=0.f;
    for (int t=0;t<T_;++t) acc = fmaf(sOut[t][tid], sSc[t], acc);
    sPool[tid]=acc;
  }
  __syncthreads();
  float v = (tid<H_)? sPool[tid]*Wc[tid] : 0.f;
  sRed[tid]=v; __syncthreads();
  for (int s=128;s>0;s>>=1){ if (tid<s) sRed[tid]+=sRed[tid+s]; __syncthreads(); }
  if (tid==0) out[b] = sRed[0] + bc[0];
}

extern "C" void kernel_launch(void* const* d_in, const int* in_sizes, int n_in,
                              void* d_out, int out_size, void* d_ws, size_t ws_size,
                              hipStream_t stream)
{
  const float* code_x=(const float*)d_in[0];
  const int*   divided=(const int*)d_in[1];
  const float* neighbors=(const float*)d_in[2];
  const int*   lens=(const int*)d_in[3];
  const float* prior=(const float*)d_in[4];
  const float* adj=(const float*)d_in[5];
  const float* c_emb=(const float*)d_in[6];
  const float* n_emb=(const float*)d_in[7];
  const float* u_emb=(const float*)d_in[8];
  const float* Wg=(const float*)d_in[9];
  const float* bg=(const float*)d_in[10];
  const float* W_ih=(const float*)d_in[11];
  const float* b_ih=(const float*)d_in[12];
  const float* W_hh=(const float*)d_in[13];
  const float* b_hh=(const float*)d_in[14];
  const float* Wq=(const float*)d_in[15];
  const float* bq=(const float*)d_in[16];
  const float* Wk=(const float*)d_in[17];
  const float* bk=(const float*)d_in[18];
  const float* Wv=(const float*)d_in[19];
  const float* bv=(const float*)d_in[20];
  const float* Wp=(const float*)d_in[21];
  const float* bp=(const float*)d_in[22];
  const float* ctx=(const float*)d_in[23];
  const float* Wc=(const float*)d_in[24];
  const float* bc=(const float*)d_in[25];
  float* out=(float*)d_out;
  (void)in_sizes; (void)n_in; (void)out_size; (void)ws_size; (void)bk;

  char* p=(char*)d_ws;
  size_t off=0;
  auto carve=[&](size_t bytes)->char*{ char* r=p+off; off=(off+bytes+255)&~(size_t)255; return r; };
  int*   rowptr=(int*)carve((N_+1)*4);
  int*   rcnt  =(int*)carve(N_*4);
  int*   ccol  =(int*)carve((size_t)NNZ_CAP*4);
  float* cval  =(float*)carve((size_t)NNZ_CAP*4);
  int*   cnt23 =(int*)carve(B_*T_*4);
  int*   cnt1  =(int*)carve(B_*T_*4);
  int*   lst23 =(int*)carve((size_t)B_*T_*N_*4);
  int*   pos1  =(int*)carve((size_t)B_*T_*N_*4);
  float* co    =(float*)carve((size_t)B_*T_*N_*G_*4);
  float* no_   =(float*)carve((size_t)B_*T_*N_*G_*4);
  float* WihT  =(float*)carve((size_t)G_*H3_*4);
  float* WhhT  =(float*)carve((size_t)H_*H3_*4);
  float* Md    =(float*)carve(1056*4);
  float* WvT   =(float*)carve((size_t)H_*G_*4);
  float* hsel  =(float*)carve((size_t)B_*T_*CAP1*H_*4);
  float* gout  =(float*)carve((size_t)B_*T_*CAP1*H_*4);
  unsigned* chainsN=(unsigned*)carve((size_t)CHCAP*4);
  unsigned* chainsH=(unsigned*)carve((size_t)CHCAP*4);
  unsigned* chainsL=(unsigned*)carve((size_t)CHCAPL*4);
  int*   nchN  =(int*)carve(256);
  int*   nchH  =(int*)carve(256);
  int*   nchL  =(int*)carve(256);
  float* om1f  =(float*)carve((size_t)B_*T_*H_*4);
  float* om23f =(float*)carve((size_t)B_*T_*H_*4);

  k_csr_cnt<<<N_,256,0,stream>>>(adj, rcnt);
  k_csr_scan<<<1,64,0,stream>>>(rcnt, rowptr);
  k_csr_fill<<<N_,64,0,stream>>>(adj, prior, rowptr, ccol, cval);
  k_masks<<<B_*T_,64,0,stream>>>(divided, lst23, pos1, cnt23, cnt1);
  k_wt<<<343,256,0,stream>>>(W_ih, W_hh, Wq, bq, Wk, Wv, WihT, WhhT, Md, WvT);
  k_init<<<(B_*T_*H_+255)/256,256,0,stream>>>(om23f, nchN, nchH, nchL);
  k_chains<<<(B_*N_+255)/256,256,0,stream>>>(divided, chainsN, nchN, chainsH, nchH, chainsL, nchL);
  k_cono<<<B_*T_*N_/4,256,0,stream>>>(code_x, neighbors, divided, rowptr, ccol, cval,
                                      c_emb, n_emb, Wg, bg, co, no_);
  k_attn<<<dim3(B_, T_-1),768,0,stream>>>(co, no_, u_emb, divided,
                                      lst23, cnt23, pos1, Md, WvT, bv,
                                      hsel, om23f);
  k_gruheadN<<<CHCAP/16,256,0,stream>>>(co, pos1, chainsN, nchN,
                                      WihT, b_ih, b_hh, gout);
  k_gruheadH<<<CHCAP/16,256,0,stream>>>(co, hsel, pos1, chainsH, nchH,
                                      WihT, b_ih, WhhT, b_hh, gout);
  k_grutail<<<CHCAPL/16,256,0,stream>>>(co, pos1, chainsL, nchL,
                                      WihT, b_ih, WhhT, b_hh, gout);
  k_om1<<<B_*T_,256,0,stream>>>(gout, cnt1, om1f);
  k_final<<<B_,256,0,stream>>>(om1f, om23f, Wp,bp,ctx,Wc,bc, lens, out);
}